// Round 1
// baseline (2523.007 us; speedup 1.0000x reference)
//
#include <hip/hip_runtime.h>
#include <hip/hip_bf16.h>

#define S_LEN 2048
#define DMODEL 4096
#define NQH 32
#define NKVH 4
#define DKH 128
#define GRPS 8

typedef __attribute__((ext_vector_type(8))) short bf16x8;
typedef __attribute__((ext_vector_type(4))) float f32x4;

// C[M,N] = A[M,K] @ B[K,N]. A: float or bf16 (row-major), B: float (row-major).
// Inputs converted to bf16 at LDS staging; fp32 MFMA accumulate.
template <typename AT, typename OT>
__global__ __launch_bounds__(256) void gemm_kernel(
    const AT* __restrict__ A, const float* __restrict__ B, OT* __restrict__ C,
    int M, int N, int K) {
  __shared__ __align__(16) __hip_bfloat16 As[128][40];
  __shared__ __align__(16) __hip_bfloat16 Bs[128][40];  // transposed: [col][k]
  const int tid = threadIdx.x;
  const int lane = tid & 63;
  const int wid = tid >> 6;
  const int wr = (wid >> 1) * 64, wc = (wid & 1) * 64;
  const int l15 = lane & 15, l4 = lane >> 4;
  const int bm = blockIdx.y * 128, bn = blockIdx.x * 128;

  f32x4 acc[4][4] = {};

  for (int k0 = 0; k0 < K; k0 += 32) {
    // stage A tile: 128 rows x 32 k
#pragma unroll
    for (int i = 0; i < 4; ++i) {
      const int row = i * 32 + (tid >> 3);
      const int kk = (tid & 7) * 4;
      if constexpr (sizeof(AT) == 4) {
        const float4 v = *reinterpret_cast<const float4*>(
            &A[(size_t)(bm + row) * K + k0 + kk]);
        As[row][kk + 0] = __float2bfloat16(v.x);
        As[row][kk + 1] = __float2bfloat16(v.y);
        As[row][kk + 2] = __float2bfloat16(v.z);
        As[row][kk + 3] = __float2bfloat16(v.w);
      } else {
        const AT* p = &A[(size_t)(bm + row) * K + k0 + kk];
        As[row][kk + 0] = p[0];
        As[row][kk + 1] = p[1];
        As[row][kk + 2] = p[2];
        As[row][kk + 3] = p[3];
      }
    }
    // stage B tile: 32 k x 128 cols, transposed into Bs[col][k]
#pragma unroll
    for (int i = 0; i < 4; ++i) {
      const int kk = i * 8 + (tid >> 5);
      const int col = (tid & 31) * 4;
      const float4 v = *reinterpret_cast<const float4*>(
          &B[(size_t)(k0 + kk) * N + bn + col]);
      Bs[col + 0][kk] = __float2bfloat16(v.x);
      Bs[col + 1][kk] = __float2bfloat16(v.y);
      Bs[col + 2][kk] = __float2bfloat16(v.z);
      Bs[col + 3][kk] = __float2bfloat16(v.w);
    }
    __syncthreads();

    bf16x8 af[4], bfr[4];
#pragma unroll
    for (int m = 0; m < 4; ++m)
      af[m] = *reinterpret_cast<const bf16x8*>(&As[wr + m * 16 + l15][l4 * 8]);
#pragma unroll
    for (int n = 0; n < 4; ++n)
      bfr[n] = *reinterpret_cast<const bf16x8*>(&Bs[wc + n * 16 + l15][l4 * 8]);
#pragma unroll
    for (int m = 0; m < 4; ++m)
#pragma unroll
      for (int n = 0; n < 4; ++n)
        acc[m][n] = __builtin_amdgcn_mfma_f32_16x16x32_bf16(af[m], bfr[n],
                                                            acc[m][n], 0, 0, 0);
    __syncthreads();
  }

#pragma unroll
  for (int m = 0; m < 4; ++m)
#pragma unroll
    for (int n = 0; n < 4; ++n)
#pragma unroll
      for (int r = 0; r < 4; ++r) {
        const int row = bm + wr + m * 16 + l4 * 4 + r;
        const int col = bn + wc + n * 16 + l15;
        if constexpr (sizeof(OT) == 4)
          C[(size_t)row * N + col] = acc[m][n][r];
        else
          C[(size_t)row * N + col] = __float2bfloat16(acc[m][n][r]);
      }
}

// Flash-style GQA attention with the reference's ANTI-causal mask:
// allowed iff kv > q, masked entries = -1e9 (finite). Tiles fully masked for
// the whole block are skipped (exact: exp(-1e9 - m_real) == 0 in f32); the
// only rows affected by the skip (q == S-1, fully-masked -> uniform softmax)
// are overwritten by fixup_kernel afterwards.
__global__ __launch_bounds__(256) void attn_kernel(
    const __hip_bfloat16* __restrict__ Q, const __hip_bfloat16* __restrict__ Kb,
    const __hip_bfloat16* __restrict__ Vb, __hip_bfloat16* __restrict__ O) {
  __shared__ __align__(16) __hip_bfloat16 Vs[128][40];     // [dk][kv]
  __shared__ __align__(16) __hip_bfloat16 Ps[4][16][40];   // per-wave P
  const int tid = threadIdx.x, lane = tid & 63, w = tid >> 6;
  const int l15 = lane & 15, l4 = lane >> 4;
  const int bh = blockIdx.y;
  const int b = bh >> 5;         // / NQH
  const int h = bh & 31;
  const int kvh = h >> 3;        // / GRPS
  const int q0 = blockIdx.x * 64;
  const int qw = q0 + w * 16;
  const size_t qbase = (size_t)b * S_LEN * DMODEL + (size_t)h * DKH;
  const size_t kvbase = (size_t)b * S_LEN * (NKVH * DKH) + (size_t)kvh * DKH;
  const float scale = 0.08838834764831843f;  // 1/sqrt(128)

  bf16x8 qf[4];
#pragma unroll
  for (int kb = 0; kb < 4; ++kb)
    qf[kb] = *reinterpret_cast<const bf16x8*>(
        &Q[qbase + (size_t)(qw + l15) * DMODEL + kb * 32 + l4 * 8]);

  float mrow[4], lrow[4];
#pragma unroll
  for (int r = 0; r < 4; ++r) { mrow[r] = -INFINITY; lrow[r] = 0.f; }
  f32x4 oacc[8] = {};

  const int t0 = q0 / 32;  // tiles t < t0 are fully masked for all 64 rows
  for (int t = t0; t < S_LEN / 32; ++t) {
    const int kv0 = t * 32;
    __syncthreads();  // protect Vs from previous iteration's readers
    // stage V tile transposed: Vs[dk][kv]
#pragma unroll
    for (int i = 0; i < 4; ++i) {
      const int kv = i * 8 + (tid >> 5);
      const int dk = (tid & 31) * 4;
      const __hip_bfloat16* pv =
          &Vb[kvbase + (size_t)(kv0 + kv) * (NKVH * DKH) + dk];
      Vs[dk + 0][kv] = pv[0];
      Vs[dk + 1][kv] = pv[1];
      Vs[dk + 2][kv] = pv[2];
      Vs[dk + 3][kv] = pv[3];
    }
    __syncthreads();

    // QK^T: scores 16q x 32kv per wave (2 col-fragments)
    f32x4 sf[2];
#pragma unroll
    for (int c = 0; c < 2; ++c) {
      f32x4 s = {};
#pragma unroll
      for (int kb = 0; kb < 4; ++kb) {
        bf16x8 kf = *reinterpret_cast<const bf16x8*>(
            &Kb[kvbase + (size_t)(kv0 + c * 16 + l15) * (NKVH * DKH) +
                kb * 32 + l4 * 8]);
        s = __builtin_amdgcn_mfma_f32_16x16x32_bf16(qf[kb], kf, s, 0, 0, 0);
      }
      sf[c] = s;
    }

    // mask (anti-causal: allowed iff kv > q) + scale
    float val[2][4], rmax[4];
#pragma unroll
    for (int r = 0; r < 4; ++r) {
      const int qa = qw + l4 * 4 + r;
      const float v0 = (kv0 + l15 > qa) ? sf[0][r] * scale : -1e9f;
      const float v1 = (kv0 + 16 + l15 > qa) ? sf[1][r] * scale : -1e9f;
      val[0][r] = v0; val[1][r] = v1;
      rmax[r] = fmaxf(v0, v1);
    }
#pragma unroll
    for (int mm = 1; mm < 16; mm <<= 1)
#pragma unroll
      for (int r = 0; r < 4; ++r)
        rmax[r] = fmaxf(rmax[r], __shfl_xor(rmax[r], mm, 64));

    float alpha[4], psum[4];
#pragma unroll
    for (int r = 0; r < 4; ++r) {
      const float mn = fmaxf(mrow[r], rmax[r]);
      alpha[r] = __expf(mrow[r] - mn);  // first tile: exp(-inf)=0, no NaN
      mrow[r] = mn;
      const float p0 = __expf(val[0][r] - mn);
      const float p1 = __expf(val[1][r] - mn);
      val[0][r] = p0; val[1][r] = p1;
      psum[r] = p0 + p1;
    }
#pragma unroll
    for (int mm = 1; mm < 16; mm <<= 1)
#pragma unroll
      for (int r = 0; r < 4; ++r)
        psum[r] += __shfl_xor(psum[r], mm, 64);
#pragma unroll
    for (int r = 0; r < 4; ++r) lrow[r] = lrow[r] * alpha[r] + psum[r];
#pragma unroll
    for (int n = 0; n < 8; ++n)
#pragma unroll
      for (int r = 0; r < 4; ++r) oacc[n][r] *= alpha[r];

    // P (C-layout) -> LDS -> A-fragment layout. Per-wave buffer, same-wave
    // in-order DS ops: no barrier needed.
#pragma unroll
    for (int c = 0; c < 2; ++c)
#pragma unroll
      for (int r = 0; r < 4; ++r)
        Ps[w][l4 * 4 + r][c * 16 + l15] = __float2bfloat16(val[c][r]);
    const bf16x8 pf = *reinterpret_cast<const bf16x8*>(&Ps[w][l15][l4 * 8]);

    // PV: out[16q][128dk] += P[16x32] @ V[32x128]
#pragma unroll
    for (int n = 0; n < 8; ++n) {
      const bf16x8 vf =
          *reinterpret_cast<const bf16x8*>(&Vs[n * 16 + l15][l4 * 8]);
      oacc[n] = __builtin_amdgcn_mfma_f32_16x16x32_bf16(pf, vf, oacc[n], 0, 0, 0);
    }
  }

  float rinv[4];
#pragma unroll
  for (int r = 0; r < 4; ++r) rinv[r] = 1.f / lrow[r];
#pragma unroll
  for (int n = 0; n < 8; ++n)
#pragma unroll
    for (int r = 0; r < 4; ++r) {
      const int row = qw + l4 * 4 + r;
      const int col = h * DKH + n * 16 + l15;
      O[(size_t)(b * S_LEN + row) * DMODEL + col] =
          __float2bfloat16(oacc[n][r] * rinv[r]);
    }
}

// Row q = S-1 is fully masked in the reference -> softmax over constant -1e9
// row -> uniform weights over ALL kv -> output = mean of V. Overwrite it.
__global__ __launch_bounds__(128) void fixup_kernel(
    const __hip_bfloat16* __restrict__ Vb, __hip_bfloat16* __restrict__ O) {
  const int b = blockIdx.x >> 5;
  const int h = blockIdx.x & 31;
  const int kvh = h >> 3;
  const int dk = threadIdx.x;
  float s = 0.f;
  for (int i = 0; i < S_LEN; ++i)
    s += __bfloat162float(
        Vb[(size_t)(b * S_LEN + i) * (NKVH * DKH) + kvh * DKH + dk]);
  O[(size_t)(b * S_LEN + S_LEN - 1) * DMODEL + h * DKH + dk] =
      __float2bfloat16(s * (1.f / S_LEN));
}

extern "C" void kernel_launch(void* const* d_in, const int* in_sizes, int n_in,
                              void* d_out, int out_size, void* d_ws,
                              size_t ws_size, hipStream_t stream) {
  const float* x = (const float*)d_in[0];
  const float* Wq = (const float*)d_in[1];
  const float* Wk = (const float*)d_in[2];
  const float* Wv = (const float*)d_in[3];
  const float* Wo = (const float*)d_in[4];
  float* out = (float*)d_out;

  char* ws = (char*)d_ws;
  __hip_bfloat16* Qb = (__hip_bfloat16*)ws;                     // 4096x4096 bf16
  __hip_bfloat16* Kb = (__hip_bfloat16*)(ws + 33554432ull);     // 4096x512
  __hip_bfloat16* Vb = (__hip_bfloat16*)(ws + 37748736ull);     // 4096x512
  __hip_bfloat16* AO = (__hip_bfloat16*)(ws + 41943040ull);     // 4096x4096

  const int M = 2 * S_LEN;  // 4096
  dim3 blk(256);

  gemm_kernel<float, __hip_bfloat16>
      <<<dim3(DMODEL / 128, M / 128), blk, 0, stream>>>(x, Wq, Qb, M, DMODEL,
                                                        DMODEL);
  gemm_kernel<float, __hip_bfloat16>
      <<<dim3((NKVH * DKH) / 128, M / 128), blk, 0, stream>>>(
          x, Wk, Kb, M, NKVH * DKH, DMODEL);
  gemm_kernel<float, __hip_bfloat16>
      <<<dim3((NKVH * DKH) / 128, M / 128), blk, 0, stream>>>(
          x, Wv, Vb, M, NKVH * DKH, DMODEL);

  attn_kernel<<<dim3(S_LEN / 64, 2 * NQH), blk, 0, stream>>>(Qb, Kb, Vb, AO);
  fixup_kernel<<<dim3(2 * NQH), dim3(128), 0, stream>>>(Vb, AO);

  gemm_kernel<__hip_bfloat16, float>
      <<<dim3(DMODEL / 128, M / 128), blk, 0, stream>>>(AO, Wo, out, M, DMODEL,
                                                        DMODEL);
}

// Round 2
// 1182.309 us; speedup vs baseline: 2.1340x; 2.1340x over previous
//
#include <hip/hip_runtime.h>
#include <hip/hip_bf16.h>

#define S_LEN 2048
#define DMODEL 4096
#define NQH 32
#define NKVH 4
#define DKH 128

typedef __attribute__((ext_vector_type(8))) short bf16x8;
typedef __attribute__((ext_vector_type(4))) float f32x4;

__device__ __forceinline__ float b2f(short u) {
  union { float f; unsigned int i; } cv;
  cv.i = ((unsigned int)(unsigned short)u) << 16;
  return cv.f;
}

__device__ __forceinline__ void gload16(const void* g, void* l) {
  __builtin_amdgcn_global_load_lds(
      (const __attribute__((address_space(1))) void*)g,
      (__attribute__((address_space(3))) void*)l, 16, 0, 0);
}

// f32 -> bf16 elementwise (vectorized: float4 in, 8B out)
__global__ __launch_bounds__(256) void cast_kernel(
    const float* __restrict__ in, __hip_bfloat16* __restrict__ out, int n4) {
  for (int i = blockIdx.x * 256 + threadIdx.x; i < n4; i += gridDim.x * 256) {
    const float4 v = reinterpret_cast<const float4*>(in)[i];
    __hip_bfloat16 t[4] = {__float2bfloat16(v.x), __float2bfloat16(v.y),
                           __float2bfloat16(v.z), __float2bfloat16(v.w)};
    reinterpret_cast<uint2*>(out)[i] = *reinterpret_cast<const uint2*>(t);
  }
}

// W f32 [K][N] -> WT bf16 [N][K]. 64x64 tile, XOR-swizzled LDS (conflict-free
// both phases), coalesced global reads and 16B coalesced global writes.
__global__ __launch_bounds__(256) void transpose_cast_kernel(
    const float* __restrict__ W, __hip_bfloat16* __restrict__ WT, int K, int N) {
  __shared__ __align__(16) __hip_bfloat16 tile[64][64];
  const int tid = threadIdx.x;
  const int n0 = blockIdx.x * 64, k0 = blockIdx.y * 64;
#pragma unroll
  for (int i = 0; i < 2; ++i) {
    const int fid = i * 256 + tid;
    const int r = fid >> 3, cc = fid & 7;  // k-row, 8-col chunk
    const float4 v0 = *reinterpret_cast<const float4*>(
        &W[(size_t)(k0 + r) * N + n0 + cc * 8]);
    const float4 v1 = *reinterpret_cast<const float4*>(
        &W[(size_t)(k0 + r) * N + n0 + cc * 8 + 4]);
    __hip_bfloat16 t[8] = {__float2bfloat16(v0.x), __float2bfloat16(v0.y),
                           __float2bfloat16(v0.z), __float2bfloat16(v0.w),
                           __float2bfloat16(v1.x), __float2bfloat16(v1.y),
                           __float2bfloat16(v1.z), __float2bfloat16(v1.w)};
    *reinterpret_cast<bf16x8*>(&tile[r][(cc ^ (r & 7)) << 3]) =
        *reinterpret_cast<const bf16x8*>(t);
  }
  __syncthreads();
  const int n = tid >> 2, kw = tid & 3;
#pragma unroll
  for (int i = 0; i < 2; ++i) {
    const int kc = kw + i * 4;
    __hip_bfloat16 t[8];
#pragma unroll
    for (int j = 0; j < 8; ++j) {
      const int r = kc * 8 + j;
      t[j] = tile[r][((((n >> 3) ^ (r & 7)) << 3)) + (n & 7)];
    }
    *reinterpret_cast<bf16x8*>(&WT[(size_t)(n0 + n) * K + k0 + kc * 8]) =
        *reinterpret_cast<const bf16x8*>(t);
  }
}

// m97-structure GEMM: C[M,N] = A[M,K] (bf16 row-major) @ BT[N,K]^T (bf16).
// 128x128 tile, BK=32, global_load_lds width-16 staging, 2 barriers/K-step.
// WMODE 0: f32 C row-major; 1: bf16 C row-major;
// WMODE 2: fused KV epilogue -> col<512: Kb row-major; col>=512: VT layout
//          VT[(b*512 + (col-512))*2048 + s]  (V transposed for attention).
template <int WMODE>
__global__ __launch_bounds__(256) void gemm_tn(
    const __hip_bfloat16* __restrict__ A, const __hip_bfloat16* __restrict__ BT,
    void* __restrict__ C0, void* __restrict__ C1, int M, int N, int K) {
  __shared__ __align__(16) __hip_bfloat16 As[128 * 32];
  __shared__ __align__(16) __hip_bfloat16 Bs[128 * 32];
  const int tid = threadIdx.x, lane = tid & 63, w = tid >> 6;
  const int l15 = lane & 15, l4 = lane >> 4;
  const int bm = blockIdx.y * 128, bn = blockIdx.x * 128;
  const int wr = (w >> 1) * 64, wc = (w & 1) * 64;
  const int srow = lane >> 2, scol = (lane & 3) * 8;
  const __hip_bfloat16* ga = &A[(size_t)(bm + w * 16 + srow) * K + scol];
  const __hip_bfloat16* gb = &BT[(size_t)(bn + w * 16 + srow) * K + scol];
  __hip_bfloat16* la0 = &As[w * 512];
  __hip_bfloat16* la1 = &As[(w + 4) * 512];
  __hip_bfloat16* lb0 = &Bs[w * 512];
  __hip_bfloat16* lb1 = &Bs[(w + 4) * 512];
  f32x4 acc[4][4] = {};

  for (int k0 = 0; k0 < K; k0 += 32) {
    gload16(ga, la0);
    gload16(ga + (size_t)64 * K, la1);
    gload16(gb, lb0);
    gload16(gb + (size_t)64 * K, lb1);
    ga += 32;
    gb += 32;
    __syncthreads();  // drains vmcnt (global_load_lds) + syncs waves
    bf16x8 af[4], bfr[4];
#pragma unroll
    for (int m = 0; m < 4; ++m)
      af[m] = *reinterpret_cast<const bf16x8*>(
          &As[(wr + m * 16 + l15) * 32 + l4 * 8]);
#pragma unroll
    for (int n = 0; n < 4; ++n)
      bfr[n] = *reinterpret_cast<const bf16x8*>(
          &Bs[(wc + n * 16 + l15) * 32 + l4 * 8]);
#pragma unroll
    for (int m = 0; m < 4; ++m)
#pragma unroll
      for (int n = 0; n < 4; ++n)
        acc[m][n] = __builtin_amdgcn_mfma_f32_16x16x32_bf16(af[m], bfr[n],
                                                            acc[m][n], 0, 0, 0);
    __syncthreads();  // protect LDS from next iteration's staging
  }

#pragma unroll
  for (int m = 0; m < 4; ++m)
#pragma unroll
    for (int n = 0; n < 4; ++n)
#pragma unroll
      for (int r = 0; r < 4; ++r) {
        const int row = bm + wr + m * 16 + l4 * 4 + r;
        const int col = bn + wc + n * 16 + l15;
        if constexpr (WMODE == 0) {
          ((float*)C0)[(size_t)row * N + col] = acc[m][n][r];
        } else if constexpr (WMODE == 1) {
          ((__hip_bfloat16*)C0)[(size_t)row * N + col] =
              __float2bfloat16(acc[m][n][r]);
        } else {
          if (col < 512) {
            ((__hip_bfloat16*)C0)[(size_t)row * 512 + col] =
                __float2bfloat16(acc[m][n][r]);
          } else {
            const int b = row >> 11, s = row & 2047;
            ((__hip_bfloat16*)C1)[(size_t)(b * 512 + (col - 512)) * 2048 + s] =
                __float2bfloat16(acc[m][n][r]);
          }
        }
      }
}

// Flash-style GQA attention, reference's ANTI-causal mask (allowed iff kv>q,
// masked = -1e9). No barriers: K and V^T fragments load directly from global
// (L2-resident tiles); only per-wave P roundtrip uses LDS. Tiles fully masked
// for the whole block are skipped; row S-1 fixed up afterwards.
__global__ __launch_bounds__(256) void attn_kernel(
    const __hip_bfloat16* __restrict__ Q, const __hip_bfloat16* __restrict__ Kb,
    const __hip_bfloat16* __restrict__ VT, __hip_bfloat16* __restrict__ O) {
  __shared__ __align__(16) __hip_bfloat16 Ps[4][16][40];
  const int tid = threadIdx.x, lane = tid & 63, w = tid >> 6;
  const int l15 = lane & 15, l4 = lane >> 4;
  // XCD-aware swizzle: 2048 blocks, 8 XCDs -> 8 contiguous (b,h) per XCD
  int id = blockIdx.x + (blockIdx.y << 5);
  id = (id & 7) * 256 + (id >> 3);
  const int qb = id & 31;
  const int bh = id >> 5;
  const int b = bh >> 5;
  const int h = bh & 31;
  const int kvh = h >> 3;
  const int q0 = qb * 64;
  const int qw = q0 + w * 16;
  const size_t qbase = (size_t)(b * S_LEN) * DMODEL + (size_t)h * DKH;
  const size_t kbase = (size_t)(b * S_LEN) * 512 + (size_t)kvh * DKH;
  const size_t vtbase = (size_t)(b * 512 + kvh * DKH) * S_LEN;
  const float scale = 0.08838834764831843f;  // 1/sqrt(128)

  bf16x8 qf[4];
#pragma unroll
  for (int kb = 0; kb < 4; ++kb)
    qf[kb] = *reinterpret_cast<const bf16x8*>(
        &Q[qbase + (size_t)(qw + l15) * DMODEL + kb * 32 + l4 * 8]);

  float mrow[4], lrow[4];
#pragma unroll
  for (int r = 0; r < 4; ++r) { mrow[r] = -INFINITY; lrow[r] = 0.f; }
  f32x4 oacc[8] = {};

  for (int t = q0 / 32; t < S_LEN / 32; ++t) {
    const int kv0 = t * 32;
    // QK^T: 16q x 32kv per wave, K fragments straight from global
    f32x4 sf[2];
#pragma unroll
    for (int c = 0; c < 2; ++c) {
      f32x4 s = {};
#pragma unroll
      for (int kb = 0; kb < 4; ++kb) {
        const bf16x8 kf = *reinterpret_cast<const bf16x8*>(
            &Kb[kbase + (size_t)(kv0 + c * 16 + l15) * 512 + kb * 32 + l4 * 8]);
        s = __builtin_amdgcn_mfma_f32_16x16x32_bf16(qf[kb], kf, s, 0, 0, 0);
      }
      sf[c] = s;
    }

    // mask + scale + online softmax
    float val[2][4], rmax[4];
#pragma unroll
    for (int r = 0; r < 4; ++r) {
      const int qa = qw + l4 * 4 + r;
      const float v0 = (kv0 + l15 > qa) ? sf[0][r] * scale : -1e9f;
      const float v1 = (kv0 + 16 + l15 > qa) ? sf[1][r] * scale : -1e9f;
      val[0][r] = v0;
      val[1][r] = v1;
      rmax[r] = fmaxf(v0, v1);
    }
#pragma unroll
    for (int mm = 1; mm < 16; mm <<= 1)
#pragma unroll
      for (int r = 0; r < 4; ++r)
        rmax[r] = fmaxf(rmax[r], __shfl_xor(rmax[r], mm, 64));

    float alpha[4], psum[4];
#pragma unroll
    for (int r = 0; r < 4; ++r) {
      const float mn = fmaxf(mrow[r], rmax[r]);
      alpha[r] = __expf(mrow[r] - mn);  // first tile: exp(-inf)=0
      mrow[r] = mn;
      const float p0 = __expf(val[0][r] - mn);
      const float p1 = __expf(val[1][r] - mn);
      val[0][r] = p0;
      val[1][r] = p1;
      psum[r] = p0 + p1;
    }
#pragma unroll
    for (int mm = 1; mm < 16; mm <<= 1)
#pragma unroll
      for (int r = 0; r < 4; ++r) psum[r] += __shfl_xor(psum[r], mm, 64);
#pragma unroll
    for (int r = 0; r < 4; ++r) lrow[r] = lrow[r] * alpha[r] + psum[r];
#pragma unroll
    for (int n = 0; n < 8; ++n)
#pragma unroll
      for (int r = 0; r < 4; ++r) oacc[n][r] *= alpha[r];

    // P (C-layout) -> per-wave LDS -> A-fragment (same-wave ds order: no bar)
#pragma unroll
    for (int c = 0; c < 2; ++c)
#pragma unroll
      for (int r = 0; r < 4; ++r)
        Ps[w][l4 * 4 + r][c * 16 + l15] = __float2bfloat16(val[c][r]);
    const bf16x8 pf = *reinterpret_cast<const bf16x8*>(&Ps[w][l15][l4 * 8]);

    // PV: V^T fragments straight from global
#pragma unroll
    for (int n = 0; n < 8; ++n) {
      const bf16x8 vf = *reinterpret_cast<const bf16x8*>(
          &VT[vtbase + (size_t)(n * 16 + l15) * S_LEN + kv0 + l4 * 8]);
      oacc[n] =
          __builtin_amdgcn_mfma_f32_16x16x32_bf16(pf, vf, oacc[n], 0, 0, 0);
    }
  }

  float rinv[4];
#pragma unroll
  for (int r = 0; r < 4; ++r) rinv[r] = 1.f / lrow[r];
#pragma unroll
  for (int n = 0; n < 8; ++n)
#pragma unroll
    for (int r = 0; r < 4; ++r) {
      const int row = qw + l4 * 4 + r;
      const int col = h * DKH + n * 16 + l15;
      O[(size_t)(b * S_LEN + row) * DMODEL + col] =
          __float2bfloat16(oacc[n][r] * rinv[r]);
    }
}

// Row q=S-1 is fully masked -> uniform softmax over all kv -> mean of V.
// Reads V^T rows (contiguous).
__global__ __launch_bounds__(128) void fixup_kernel(
    const __hip_bfloat16* __restrict__ VT, __hip_bfloat16* __restrict__ O) {
  const int b = blockIdx.x >> 5;
  const int h = blockIdx.x & 31;
  const int kvh = h >> 3;
  const int dk = threadIdx.x;
  const __hip_bfloat16* row = &VT[(size_t)(b * 512 + kvh * DKH + dk) * S_LEN];
  float s = 0.f;
  for (int i = 0; i < S_LEN / 8; ++i) {
    const bf16x8 v = *reinterpret_cast<const bf16x8*>(&row[i * 8]);
#pragma unroll
    for (int j = 0; j < 8; ++j) s += b2f(v[j]);
  }
  O[(size_t)(b * S_LEN + S_LEN - 1) * DMODEL + h * DKH + dk] =
      __float2bfloat16(s * (1.f / S_LEN));
}

extern "C" void kernel_launch(void* const* d_in, const int* in_sizes, int n_in,
                              void* d_out, int out_size, void* d_ws,
                              size_t ws_size, hipStream_t stream) {
  (void)in_sizes; (void)n_in; (void)out_size; (void)ws_size;
  const float* x = (const float*)d_in[0];
  const float* Wq = (const float*)d_in[1];
  const float* Wk = (const float*)d_in[2];
  const float* Wv = (const float*)d_in[3];
  const float* Wo = (const float*)d_in[4];
  float* out = (float*)d_out;

  char* ws = (char*)d_ws;
  // layout (bytes):
  __hip_bfloat16* xb  = (__hip_bfloat16*)(ws + 0);            // 32MB (reused as AO)
  __hip_bfloat16* WT0 = (__hip_bfloat16*)(ws + 33554432ull);  // 32MB (WqT, later WoT)
  __hip_bfloat16* KVT = (__hip_bfloat16*)(ws + 67108864ull);  // 8MB  (WkT|WvT)
  __hip_bfloat16* Qb  = (__hip_bfloat16*)(ws + 75497472ull);  // 32MB
  __hip_bfloat16* Kb  = (__hip_bfloat16*)(ws + 109051904ull); // 4MB
  __hip_bfloat16* VT  = (__hip_bfloat16*)(ws + 113246208ull); // 4MB
  __hip_bfloat16* AO  = xb;  // x dead after KV gemm

  const int M = 2 * S_LEN;  // 4096
  dim3 blk(256);

  // 1. cast x -> bf16
  cast_kernel<<<dim3(2048), blk, 0, stream>>>(x, xb, (M * DMODEL) / 4);
  // 2. Wq^T
  transpose_cast_kernel<<<dim3(64, 64), blk, 0, stream>>>(Wq, WT0, DMODEL, DMODEL);
  // 3. Q = x @ Wq  (bf16 out)
  gemm_tn<1><<<dim3(32, 32), blk, 0, stream>>>(xb, WT0, Qb, nullptr, M, DMODEL, DMODEL);
  // 4. Wk^T, Wv^T (concatenated -> one N=1024 GEMM)
  transpose_cast_kernel<<<dim3(8, 64), blk, 0, stream>>>(Wk, KVT, DMODEL, 512);
  transpose_cast_kernel<<<dim3(8, 64), blk, 0, stream>>>(Wv, KVT + 512ull * DMODEL, DMODEL, 512);
  // 5. K (row-major) + V (transposed) in one GEMM
  gemm_tn<2><<<dim3(8, 32), blk, 0, stream>>>(xb, KVT, Kb, VT, M, 1024, DMODEL);
  // 6. attention -> AO (aliases xb)
  attn_kernel<<<dim3(32, 64), blk, 0, stream>>>(Qb, Kb, VT, AO);
  fixup_kernel<<<dim3(64), dim3(128), 0, stream>>>(VT, AO);
  // 7. Wo^T (reuse WT0)
  transpose_cast_kernel<<<dim3(64, 64), blk, 0, stream>>>(Wo, WT0, DMODEL, DMODEL);
  // 8. out = AO @ Wo  (f32 out)
  gemm_tn<0><<<dim3(32, 32), blk, 0, stream>>>(AO, WT0, out, nullptr, M, DMODEL, DMODEL);
}

// Round 3
// 689.339 us; speedup vs baseline: 3.6600x; 1.7151x over previous
//
#include <hip/hip_runtime.h>
#include <hip/hip_bf16.h>

#define S_LEN 2048
#define DMODEL 4096
#define NQH 32
#define NKVH 4
#define DKH 128

typedef __attribute__((ext_vector_type(8))) short bf16x8;
typedef __attribute__((ext_vector_type(4))) float f32x4;

union PU { unsigned u[4]; bf16x8 v; };

__device__ __forceinline__ float b2f(short u) {
  union { float f; unsigned int i; } cv;
  cv.i = ((unsigned int)(unsigned short)u) << 16;
  return cv.f;
}

__device__ __forceinline__ unsigned cvt_pk(float lo, float hi) {
  unsigned r;
  asm("v_cvt_pk_bf16_f32 %0, %1, %2" : "=v"(r) : "v"(lo), "v"(hi));
  return r;
}

__device__ __forceinline__ void gload16(const void* g, void* l) {
  __builtin_amdgcn_global_load_lds(
      (const __attribute__((address_space(1))) void*)g,
      (__attribute__((address_space(3))) void*)l, 16, 0, 0);
}

// f32 -> bf16 elementwise (vectorized: float4 in, 8B out)
__global__ __launch_bounds__(256) void cast_kernel(
    const float* __restrict__ in, __hip_bfloat16* __restrict__ out, int n4) {
  for (int i = blockIdx.x * 256 + threadIdx.x; i < n4; i += gridDim.x * 256) {
    const float4 v = reinterpret_cast<const float4*>(in)[i];
    __hip_bfloat16 t[4] = {__float2bfloat16(v.x), __float2bfloat16(v.y),
                           __float2bfloat16(v.z), __float2bfloat16(v.w)};
    reinterpret_cast<uint2*>(out)[i] = *reinterpret_cast<const uint2*>(t);
  }
}

// W f32 [K][N] -> WT bf16 [N][K]. 64x64 tile, XOR-swizzled LDS.
__global__ __launch_bounds__(256) void transpose_cast_kernel(
    const float* __restrict__ W, __hip_bfloat16* __restrict__ WT, int K, int N) {
  __shared__ __align__(16) __hip_bfloat16 tile[64][64];
  const int tid = threadIdx.x;
  const int n0 = blockIdx.x * 64, k0 = blockIdx.y * 64;
#pragma unroll
  for (int i = 0; i < 2; ++i) {
    const int fid = i * 256 + tid;
    const int r = fid >> 3, cc = fid & 7;
    const float4 v0 = *reinterpret_cast<const float4*>(
        &W[(size_t)(k0 + r) * N + n0 + cc * 8]);
    const float4 v1 = *reinterpret_cast<const float4*>(
        &W[(size_t)(k0 + r) * N + n0 + cc * 8 + 4]);
    __hip_bfloat16 t[8] = {__float2bfloat16(v0.x), __float2bfloat16(v0.y),
                           __float2bfloat16(v0.z), __float2bfloat16(v0.w),
                           __float2bfloat16(v1.x), __float2bfloat16(v1.y),
                           __float2bfloat16(v1.z), __float2bfloat16(v1.w)};
    *reinterpret_cast<bf16x8*>(&tile[r][(cc ^ (r & 7)) << 3]) =
        *reinterpret_cast<const bf16x8*>(t);
  }
  __syncthreads();
  const int n = tid >> 2, kw = tid & 3;
#pragma unroll
  for (int i = 0; i < 2; ++i) {
    const int kc = kw + i * 4;
    __hip_bfloat16 t[8];
#pragma unroll
    for (int j = 0; j < 8; ++j) {
      const int r = kc * 8 + j;
      t[j] = tile[r][((((n >> 3) ^ (r & 7)) << 3)) + (n & 7)];
    }
    *reinterpret_cast<bf16x8*>(&WT[(size_t)(n0 + n) * K + k0 + kc * 8]) =
        *reinterpret_cast<const bf16x8*>(t);
  }
}

// m97-structure GEMM: C[M,N] = A[M,K] (bf16) @ BT[N,K]^T (bf16).
// WMODE 0: f32 C; 1: bf16 C; 2: fused KV epilogue (K row-major | V transposed)
template <int WMODE>
__global__ __launch_bounds__(256) void gemm_tn(
    const __hip_bfloat16* __restrict__ A, const __hip_bfloat16* __restrict__ BT,
    void* __restrict__ C0, void* __restrict__ C1, int M, int N, int K) {
  __shared__ __align__(16) __hip_bfloat16 As[128 * 32];
  __shared__ __align__(16) __hip_bfloat16 Bs[128 * 32];
  const int tid = threadIdx.x, lane = tid & 63, w = tid >> 6;
  const int l15 = lane & 15, l4 = lane >> 4;
  const int bm = blockIdx.y * 128, bn = blockIdx.x * 128;
  const int wr = (w >> 1) * 64, wc = (w & 1) * 64;
  const int srow = lane >> 2, scol = (lane & 3) * 8;
  const __hip_bfloat16* ga = &A[(size_t)(bm + w * 16 + srow) * K + scol];
  const __hip_bfloat16* gb = &BT[(size_t)(bn + w * 16 + srow) * K + scol];
  __hip_bfloat16* la0 = &As[w * 512];
  __hip_bfloat16* la1 = &As[(w + 4) * 512];
  __hip_bfloat16* lb0 = &Bs[w * 512];
  __hip_bfloat16* lb1 = &Bs[(w + 4) * 512];
  f32x4 acc[4][4] = {};

  for (int k0 = 0; k0 < K; k0 += 32) {
    gload16(ga, la0);
    gload16(ga + (size_t)64 * K, la1);
    gload16(gb, lb0);
    gload16(gb + (size_t)64 * K, lb1);
    ga += 32;
    gb += 32;
    __syncthreads();
    bf16x8 af[4], bfr[4];
#pragma unroll
    for (int m = 0; m < 4; ++m)
      af[m] = *reinterpret_cast<const bf16x8*>(
          &As[(wr + m * 16 + l15) * 32 + l4 * 8]);
#pragma unroll
    for (int n = 0; n < 4; ++n)
      bfr[n] = *reinterpret_cast<const bf16x8*>(
          &Bs[(wc + n * 16 + l15) * 32 + l4 * 8]);
#pragma unroll
    for (int m = 0; m < 4; ++m)
#pragma unroll
      for (int n = 0; n < 4; ++n)
        acc[m][n] = __builtin_amdgcn_mfma_f32_16x16x32_bf16(af[m], bfr[n],
                                                            acc[m][n], 0, 0, 0);
    __syncthreads();
  }

#pragma unroll
  for (int m = 0; m < 4; ++m)
#pragma unroll
    for (int n = 0; n < 4; ++n)
#pragma unroll
      for (int r = 0; r < 4; ++r) {
        const int row = bm + wr + m * 16 + l4 * 4 + r;
        const int col = bn + wc + n * 16 + l15;
        if constexpr (WMODE == 0) {
          ((float*)C0)[(size_t)row * N + col] = acc[m][n][r];
        } else if constexpr (WMODE == 1) {
          ((__hip_bfloat16*)C0)[(size_t)row * N + col] =
              __float2bfloat16(acc[m][n][r]);
        } else {
          if (col < 512) {
            ((__hip_bfloat16*)C0)[(size_t)row * 512 + col] =
                __float2bfloat16(acc[m][n][r]);
          } else {
            const int b = row >> 11, s = row & 2047;
            ((__hip_bfloat16*)C1)[(size_t)(b * 512 + (col - 512)) * 2048 + s] =
                __float2bfloat16(acc[m][n][r]);
          }
        }
      }
}

// Flash GQA attention, ANTI-causal mask (allowed iff kv > q, masked = -1e9).
// 512 blocks x 8 waves. Each block: balanced pair of 128-row q-ranges
// (pp, 15-pp) -> exactly 34 64-kv tiles per block (zero tail). K and V^T
// staged per block in XOR-swizzled LDS (double-buffered, global_load_lds).
// Swapped QK^T (S^T = K·Q^T): softmax is lane-local + 2 shfls; P regrouped
// to MFMA B-operand via bpermute; PV computed as O^T = V^T·P^T so the
// online-softmax rescale is lane-local. Defer-max (THR=8) skips rescales.
__global__ __launch_bounds__(512, 4) void attn_kernel(
    const __hip_bfloat16* __restrict__ Q, const __hip_bfloat16* __restrict__ Kb,
    const __hip_bfloat16* __restrict__ VT, __hip_bfloat16* __restrict__ O) {
  __shared__ __align__(16) __hip_bfloat16 Kbuf[2][64 * 128];  // 64 kv x 256B
  __shared__ __align__(16) __hip_bfloat16 Vbuf[2][128 * 64];  // 128 dk x 128B
  const int tid = threadIdx.x, lane = tid & 63, w = tid >> 6;
  const int l15 = lane & 15, g = (lane >> 4) & 3;
  const int d = blockIdx.x;
  // XCD swizzle: d%8 = KV group (b,kvh) -> each XCD L2 holds one 1MB group
  const int xg = d & 7, hh = (d >> 3) & 7, pr = d >> 6;  // pr in [0,8)
  const int bh = xg * 8 + hh;
  const int b = bh >> 5, h = bh & 31, kvh = (bh & 31) >> 3;
  const char* kbase = (const char*)Kb + (size_t)(b * S_LEN) * 1024 + kvh * 256;
  const char* vbase = (const char*)VT + (size_t)(b * 512 + kvh * 128) * 4096;
  const __hip_bfloat16* qbase =
      Q + (size_t)(b * S_LEN) * DMODEL + (size_t)h * DKH;
  __hip_bfloat16* obase = O + (size_t)(b * S_LEN) * DMODEL + (size_t)h * DKH;
  const int krr = lane >> 4, kcb = (lane & 15) * 16;  // K-stage lane coords
  const int vrr = lane >> 3, vcb = (lane & 7) * 16;   // V-stage lane coords
  char* klds = (char*)&Kbuf[0][0] + w * 2048;
  char* vlds = (char*)&Vbuf[0][0] + w * 2048;
  const int swr = (l15 & 7) * 16;  // read-side XOR swizzle

  int par = 0;
  for (int ph = 0; ph < 2; ++ph) {
    const int pp = ph ? (15 - pr) : pr;
    const int qw = pp * 128 + w * 16;
    const int qa = qw + l15;
    bf16x8 qf[4];
#pragma unroll
    for (int kb = 0; kb < 4; ++kb)
      qf[kb] = *reinterpret_cast<const bf16x8*>(
          &qbase[(size_t)(qw + l15) * DMODEL + kb * 32 + g * 8]);
    float mrow = -INFINITY, lrow = 0.f;
    f32x4 oacc[8] = {};
    const int t0 = pp * 2;
    {  // prologue stage into buf[par]
      const int kv0 = t0 * 64;
#pragma unroll
      for (int i = 0; i < 2; ++i) {
        const int rr = 8 * w + 4 * i + krr;
        gload16(kbase + (size_t)(kv0 + rr) * 1024 + (kcb ^ ((rr & 7) * 16)),
                klds + par * 16384 + i * 1024);
        const int r2 = 16 * w + 8 * i + vrr;
        gload16(vbase + (size_t)r2 * 4096 + kv0 * 2 + (vcb ^ ((r2 & 7) * 16)),
                vlds + par * 16384 + i * 1024);
      }
    }
    for (int t = t0; t < 32; ++t) {
      __syncthreads();  // drains staging vmcnt, publishes buf[par]
      if (t + 1 < 32) {  // async stage next tile into buf[par^1]
        const int kv0 = (t + 1) * 64;
        const int np = par ^ 1;
#pragma unroll
        for (int i = 0; i < 2; ++i) {
          const int rr = 8 * w + 4 * i + krr;
          gload16(kbase + (size_t)(kv0 + rr) * 1024 + (kcb ^ ((rr & 7) * 16)),
                  klds + np * 16384 + i * 1024);
          const int r2 = 16 * w + 8 * i + vrr;
          gload16(vbase + (size_t)r2 * 4096 + kv0 * 2 + (vcb ^ ((r2 & 7) * 16)),
                  vlds + np * 16384 + i * 1024);
        }
      }
      const char* kp = (const char*)&Kbuf[0][0] + par * 16384;
      const char* vp = (const char*)&Vbuf[0][0] + par * 16384;
      // QK^T swapped: sT[c] = K-frag(c) . Q^T  -> lane: q=l15, kv=16c+4g+r
      f32x4 sT[4];
#pragma unroll
      for (int c = 0; c < 4; ++c) {
        f32x4 s = {};
#pragma unroll
        for (int kb = 0; kb < 4; ++kb) {
          const bf16x8 kf = *reinterpret_cast<const bf16x8*>(
              kp + (16 * c + l15) * 256 + ((kb * 64 + g * 16) ^ swr));
          s = __builtin_amdgcn_mfma_f32_16x16x32_bf16(kf, qf[kb], s, 0, 0, 0);
        }
        sT[c] = s;
      }
      // mask + scale in place; lane-local row max
      const int dthr = qa - t * 64 - 4 * g;  // allowed iff 16c + r > dthr
      float m8 = -INFINITY;
#pragma unroll
      for (int c = 0; c < 4; ++c)
#pragma unroll
        for (int r = 0; r < 4; ++r) {
          const float v =
              (16 * c + r > dthr) ? sT[c][r] * 0.08838834764831843f : -1e9f;
          sT[c][r] = v;
          m8 = fmaxf(m8, v);
        }
      m8 = fmaxf(m8, __shfl_xor(m8, 16));
      m8 = fmaxf(m8, __shfl_xor(m8, 32));
      if (!__all(m8 - mrow <= 8.0f)) {  // defer-max: rescale only when needed
        const float mn = fmaxf(mrow, m8);
        const float al = __expf(mrow - mn);
        mrow = mn;
        lrow *= al;
#pragma unroll
        for (int n = 0; n < 8; ++n)
#pragma unroll
          for (int r = 0; r < 4; ++r) oacc[n][r] *= al;
      }
      float ps = 0.f;
#pragma unroll
      for (int c = 0; c < 4; ++c)
#pragma unroll
        for (int r = 0; r < 4; ++r) {
          const float e = __expf(sT[c][r] - mrow);
          sT[c][r] = e;
          ps += e;
        }
      ps += __shfl_xor(ps, 16);
      ps += __shfl_xor(ps, 32);
      lrow += ps;
      // pack P to bf16 pairs: P0/P1[c] = elements (4g'+{0,1}), (4g'+{2,3})
      unsigned P0[4], P1[4];
#pragma unroll
      for (int c = 0; c < 4; ++c) {
        P0[c] = cvt_pk(sT[c][0], sT[c][1]);
        P1[c] = cvt_pk(sT[c][2], sT[c][3]);
      }
      // regroup to PV B-operand: lane(g) needs kv = 32ks + 8g + [0..7]
      const int sl_lo = l15 + ((g & 1) << 5);
      const int sl_hi = sl_lo + 16;
      const bool hi = (g & 2) != 0;
#pragma unroll
      for (int ks = 0; ks < 2; ++ks) {
        const int a0 = (int)P0[2 * ks], a1 = (int)P1[2 * ks];
        const int b0 = (int)P0[2 * ks + 1], b1 = (int)P1[2 * ks + 1];
        const unsigned s0a = __shfl(a0, sl_lo), s0b = __shfl(b0, sl_lo);
        const unsigned s1a = __shfl(a1, sl_lo), s1b = __shfl(b1, sl_lo);
        const unsigned s2a = __shfl(a0, sl_hi), s2b = __shfl(b0, sl_hi);
        const unsigned s3a = __shfl(a1, sl_hi), s3b = __shfl(b1, sl_hi);
        PU pu;
        pu.u[0] = hi ? s0b : s0a;
        pu.u[1] = hi ? s1b : s1a;
        pu.u[2] = hi ? s2b : s2a;
        pu.u[3] = hi ? s3b : s3a;
        // PV as O^T = V^T . P^T : C row = dk (16n+4g+r), col = q (l15)
#pragma unroll
        for (int n = 0; n < 8; ++n) {
          const bf16x8 vf = *reinterpret_cast<const bf16x8*>(
              vp + (16 * n + l15) * 128 + ((ks * 64 + g * 16) ^ swr));
          oacc[n] =
              __builtin_amdgcn_mfma_f32_16x16x32_bf16(vf, pu.v, oacc[n], 0, 0, 0);
        }
      }
      par ^= 1;
    }
    // store O^T fragment: lane -> row q = qw+l15, cols dk = 16n+4g+[0..3]
    const float rinv = 1.f / lrow;
    __hip_bfloat16* orow = obase + (size_t)(qw + l15) * DMODEL;
#pragma unroll
    for (int n = 0; n < 8; ++n) {
      uint2 st;
      st.x = cvt_pk(oacc[n][0] * rinv, oacc[n][1] * rinv);
      st.y = cvt_pk(oacc[n][2] * rinv, oacc[n][3] * rinv);
      *reinterpret_cast<uint2*>(&orow[16 * n + 4 * g]) = st;
    }
    __syncthreads();  // inter-phase safety
  }
}

// Row q=S-1 is fully masked -> uniform softmax over all kv -> mean of V.
__global__ __launch_bounds__(128) void fixup_kernel(
    const __hip_bfloat16* __restrict__ VT, __hip_bfloat16* __restrict__ O) {
  const int b = blockIdx.x >> 5;
  const int h = blockIdx.x & 31;
  const int kvh = h >> 3;
  const int dk = threadIdx.x;
  const __hip_bfloat16* row = &VT[(size_t)(b * 512 + kvh * DKH + dk) * S_LEN];
  float s = 0.f;
  for (int i = 0; i < S_LEN / 8; ++i) {
    const bf16x8 v = *reinterpret_cast<const bf16x8*>(&row[i * 8]);
#pragma unroll
    for (int j = 0; j < 8; ++j) s += b2f(v[j]);
  }
  O[(size_t)(b * S_LEN + S_LEN - 1) * DMODEL + h * DKH + dk] =
      __float2bfloat16(s * (1.f / S_LEN));
}

extern "C" void kernel_launch(void* const* d_in, const int* in_sizes, int n_in,
                              void* d_out, int out_size, void* d_ws,
                              size_t ws_size, hipStream_t stream) {
  (void)in_sizes; (void)n_in; (void)out_size; (void)ws_size;
  const float* x = (const float*)d_in[0];
  const float* Wq = (const float*)d_in[1];
  const float* Wk = (const float*)d_in[2];
  const float* Wv = (const float*)d_in[3];
  const float* Wo = (const float*)d_in[4];
  float* out = (float*)d_out;

  char* ws = (char*)d_ws;
  __hip_bfloat16* xb  = (__hip_bfloat16*)(ws + 0);            // 32MB (reused as AO)
  __hip_bfloat16* WT0 = (__hip_bfloat16*)(ws + 33554432ull);  // 32MB
  __hip_bfloat16* KVT = (__hip_bfloat16*)(ws + 67108864ull);  // 8MB
  __hip_bfloat16* Qb  = (__hip_bfloat16*)(ws + 75497472ull);  // 32MB
  __hip_bfloat16* Kb  = (__hip_bfloat16*)(ws + 109051904ull); // 4MB
  __hip_bfloat16* VT  = (__hip_bfloat16*)(ws + 113246208ull); // 4MB
  __hip_bfloat16* AO  = xb;  // x dead after KV gemm

  const int M = 2 * S_LEN;  // 4096
  dim3 blk(256);

  cast_kernel<<<dim3(2048), blk, 0, stream>>>(x, xb, (M * DMODEL) / 4);
  transpose_cast_kernel<<<dim3(64, 64), blk, 0, stream>>>(Wq, WT0, DMODEL, DMODEL);
  gemm_tn<1><<<dim3(32, 32), blk, 0, stream>>>(xb, WT0, Qb, nullptr, M, DMODEL, DMODEL);
  transpose_cast_kernel<<<dim3(8, 64), blk, 0, stream>>>(Wk, KVT, DMODEL, 512);
  transpose_cast_kernel<<<dim3(8, 64), blk, 0, stream>>>(Wv, KVT + 512ull * DMODEL, DMODEL, 512);
  gemm_tn<2><<<dim3(8, 32), blk, 0, stream>>>(xb, KVT, Kb, VT, M, 1024, DMODEL);
  attn_kernel<<<dim3(512), dim3(512), 0, stream>>>(Qb, Kb, VT, AO);
  fixup_kernel<<<dim3(64), dim3(128), 0, stream>>>(VT, AO);
  transpose_cast_kernel<<<dim3(64, 64), blk, 0, stream>>>(Wo, WT0, DMODEL, DMODEL);
  gemm_tn<0><<<dim3(32, 32), blk, 0, stream>>>(AO, WT0, out, nullptr, M, DMODEL, DMODEL);
}

// Round 4
// 540.007 us; speedup vs baseline: 4.6722x; 1.2765x over previous
//
#include <hip/hip_runtime.h>
#include <hip/hip_bf16.h>

#define S_LEN 2048
#define DMODEL 4096
#define NQH 32
#define NKVH 4
#define DKH 128

typedef __attribute__((ext_vector_type(8))) short bf16x8;
typedef __attribute__((ext_vector_type(4))) float f32x4;

union PU { unsigned u[4]; bf16x8 v; };

__device__ __forceinline__ float b2f(short u) {
  union { float f; unsigned int i; } cv;
  cv.i = ((unsigned int)(unsigned short)u) << 16;
  return cv.f;
}

__device__ __forceinline__ unsigned cvt_pk(float lo, float hi) {
  unsigned r;
  asm("v_cvt_pk_bf16_f32 %0, %1, %2" : "=v"(r) : "v"(lo), "v"(hi));
  return r;
}

__device__ __forceinline__ void gload16(const void* g, void* l) {
  __builtin_amdgcn_global_load_lds(
      (const __attribute__((address_space(1))) void*)g,
      (__attribute__((address_space(3))) void*)l, 16, 0, 0);
}

// raw barrier: no implicit vmcnt(0) drain (that drain is the m97 ceiling)
#define BAR()                         \
  {                                   \
    asm volatile("" ::: "memory");    \
    __builtin_amdgcn_s_barrier();     \
    asm volatile("" ::: "memory");    \
  }

// f32 -> bf16 elementwise
__global__ __launch_bounds__(256) void cast_kernel(
    const float* __restrict__ in, __hip_bfloat16* __restrict__ out, int n4) {
  for (int i = blockIdx.x * 256 + threadIdx.x; i < n4; i += gridDim.x * 256) {
    const float4 v = reinterpret_cast<const float4*>(in)[i];
    __hip_bfloat16 t[4] = {__float2bfloat16(v.x), __float2bfloat16(v.y),
                           __float2bfloat16(v.z), __float2bfloat16(v.w)};
    reinterpret_cast<uint2*>(out)[i] = *reinterpret_cast<const uint2*>(t);
  }
}

// W f32 [K][N] -> WT bf16 [N][K]
__global__ __launch_bounds__(256) void transpose_cast_kernel(
    const float* __restrict__ W, __hip_bfloat16* __restrict__ WT, int K, int N) {
  __shared__ __align__(16) __hip_bfloat16 tile[64][64];
  const int tid = threadIdx.x;
  const int n0 = blockIdx.x * 64, k0 = blockIdx.y * 64;
#pragma unroll
  for (int i = 0; i < 2; ++i) {
    const int fid = i * 256 + tid;
    const int r = fid >> 3, cc = fid & 7;
    const float4 v0 = *reinterpret_cast<const float4*>(
        &W[(size_t)(k0 + r) * N + n0 + cc * 8]);
    const float4 v1 = *reinterpret_cast<const float4*>(
        &W[(size_t)(k0 + r) * N + n0 + cc * 8 + 4]);
    __hip_bfloat16 t[8] = {__float2bfloat16(v0.x), __float2bfloat16(v0.y),
                           __float2bfloat16(v0.z), __float2bfloat16(v0.w),
                           __float2bfloat16(v1.x), __float2bfloat16(v1.y),
                           __float2bfloat16(v1.z), __float2bfloat16(v1.w)};
    *reinterpret_cast<bf16x8*>(&tile[r][(cc ^ (r & 7)) << 3]) =
        *reinterpret_cast<const bf16x8*>(t);
  }
  __syncthreads();
  const int n = tid >> 2, kw = tid & 3;
#pragma unroll
  for (int i = 0; i < 2; ++i) {
    const int kc = kw + i * 4;
    __hip_bfloat16 t[8];
#pragma unroll
    for (int j = 0; j < 8; ++j) {
      const int r = kc * 8 + j;
      t[j] = tile[r][((((n >> 3) ^ (r & 7)) << 3)) + (n & 7)];
    }
    *reinterpret_cast<bf16x8*>(&WT[(size_t)(n0 + n) * K + k0 + kc * 8]) =
        *reinterpret_cast<const bf16x8*>(t);
  }
}

// ---------------- 8-phase 256x256 GEMM (4096^3, bf16 in) -------------------
// C = A[4096,4096] @ BT[4096,4096]^T. 512 thr / 8 waves; BK=64; 128KiB LDS
// (2 K-tile dbuf). Wave (wr,wcn) owns rows {qm*128+wr*64..+64} x cols
// {qn*128+wcn*32..+32} => each phase(qm,qn) touches exactly one A-half and
// one B-half => half-tiles are phase-partitioned (liveness verified):
//   ph(0,0) reads A0,B0  stages (t+1).A1   (into opposite buf, dead)
//   ph(0,1) reads A0,B1  stages (t+1).B1
//   ph(1,0) reads A1,B0  stages (t+2).A0   (own buf, A0 dead after ph(0,1))
//   ph(1,1) reads A1,B1  stages (t+2).B0   (B0 dead after ph(1,0))
// Counted vmcnt(4) gate once per tile (2 newest half-tiles stay in flight).
// T2 swizzle: LDS linear dest, source kbyte ^= (row&7)<<4, same XOR on read.
template <int QM, int QN>
__device__ __forceinline__ void phase_fn(const char* lds, f32x4 (&acc)[8][4],
                                         int pA, int pB, int rA, int rB,
                                         int okk, const char* src, char* dst) {
  bf16x8 afr[4][2], bfr[2][2];
#pragma unroll
  for (int m = 0; m < 4; ++m)
#pragma unroll
    for (int kk = 0; kk < 2; ++kk)
      afr[m][kk] = *reinterpret_cast<const bf16x8*>(
          lds + pA + QM * 16384 + rA + m * 2048 + (okk ^ (kk << 6)));
#pragma unroll
  for (int n = 0; n < 2; ++n)
#pragma unroll
    for (int kk = 0; kk < 2; ++kk)
      bfr[n][kk] = *reinterpret_cast<const bf16x8*>(
          lds + pB + QN * 16384 + rB + n * 2048 + (okk ^ (kk << 6)));
  gload16(src, dst);              // stage scheduled half-tile (2 loads/thread)
  gload16(src + 524288, dst + 8192);
  BAR();
  asm volatile("s_waitcnt lgkmcnt(0)" ::: "memory");  // reads done pre-MFMA
  __builtin_amdgcn_s_setprio(1);
#pragma unroll
  for (int kk = 0; kk < 2; ++kk)
#pragma unroll
    for (int m = 0; m < 4; ++m)
#pragma unroll
      for (int n = 0; n < 2; ++n)
        acc[QM * 4 + m][QN * 2 + n] = __builtin_amdgcn_mfma_f32_16x16x32_bf16(
            afr[m][kk], bfr[n][kk], acc[QM * 4 + m][QN * 2 + n], 0, 0, 0);
  __builtin_amdgcn_s_setprio(0);
  BAR();
}

template <int WMODE>  // 0: f32 out, 1: bf16 out
__global__ __launch_bounds__(512, 2) void gemm256(
    const __hip_bfloat16* __restrict__ A, const __hip_bfloat16* __restrict__ BT,
    void* __restrict__ C) {
  __shared__ __align__(16) char ldsA[131072];
  const char* lds = &ldsA[0];
  const int tid = threadIdx.x, lane = tid & 63, w = tid >> 6;
  const int l15 = lane & 15, g = lane >> 4;
  const int wr = w >> 2, wcn = w & 3;
  // XCD swizzle: 256 blocks % 8 == 0 -> simple bijective form
  const int id = blockIdx.x;
  const int swz = (id & 7) * 32 + (id >> 3);
  const int bm = (swz >> 4) * 256, bn = (swz & 15) * 256;
  // staging per-thread constants (source pre-swizzle = read XOR, involution)
  const int row0 = tid >> 3;  // 0..63
  const int kbg = ((tid & 7) * 16) ^ ((row0 & 7) << 4);
  const char* Ab = (const char*)A;
  const char* Bb = (const char*)BT;
  const size_t aR = (size_t)(bm + row0) * 8192 + kbg;
  const size_t bR = (size_t)(bn + row0) * 8192 + kbg;
  char* ldsw = const_cast<char*>(lds) + w * 1024;  // wave-uniform stage base
  // read-side constants
  const int sw = (l15 & 7) << 4;
  const int okk = (g * 16) ^ sw;
  const int rA = (wr * 64 + l15) * 128;
  const int rB = (wcn * 32 + l15) * 128;

  f32x4 acc[8][4] = {};

#define STG2(XR, XB, DST)            \
  gload16(XB + (XR), ldsw + (DST));  \
  gload16(XB + (XR) + 524288, ldsw + (DST) + 8192)

  // prologue: 6 half-tile stages = tile0 complete + tile1 A0,B0
  STG2(aR, Ab, 0);                        // 0.A0
  STG2(bR, Bb, 65536);                    // 0.B0
  STG2(aR + 1048576, Ab, 16384);          // 0.A1
  STG2(bR + 1048576, Bb, 65536 + 16384);  // 0.B1
  STG2(aR + 128, Ab, 32768);              // 1.A0
  STG2(bR + 128, Bb, 65536 + 32768);      // 1.B0

  for (int t = 0; t < 64; ++t) {
    const int pc = t & 1, pn = pc ^ 1;
    const int pA = pc * 32768, pB = 65536 + pc * 32768;
    const size_t s01 = (size_t)((t + 1 < 64) ? t + 1 : t - 1) * 128;
    const size_t s23 = (size_t)((t + 2 < 64) ? t + 2 : t) * 128;
    asm volatile("s_waitcnt vmcnt(4)" ::: "memory");  // tile t resident
    BAR();
    phase_fn<0, 0>(lds, acc, pA, pB, rA, rB, okk,
                   Ab + aR + 1048576 + s01, ldsw + pn * 32768 + 16384);
    phase_fn<0, 1>(lds, acc, pA, pB, rA, rB, okk,
                   Bb + bR + 1048576 + s01, ldsw + 65536 + pn * 32768 + 16384);
    phase_fn<1, 0>(lds, acc, pA, pB, rA, rB, okk,
                   Ab + aR + s23, ldsw + pc * 32768);
    phase_fn<1, 1>(lds, acc, pA, pB, rA, rB, okk,
                   Bb + bR + s23, ldsw + 65536 + pc * 32768);
  }
  asm volatile("s_waitcnt vmcnt(0)" ::: "memory");  // drain dead stages

  const int crow0 = bm + wr * 64 + g * 4;
  const int ccol0 = bn + wcn * 32 + l15;
#pragma unroll
  for (int M = 0; M < 8; ++M)
#pragma unroll
    for (int N = 0; N < 4; ++N) {
      const int row = crow0 + (M >> 2) * 128 + (M & 3) * 16;
      const int col = ccol0 + (N >> 1) * 128 + (N & 1) * 16;
#pragma unroll
      for (int r = 0; r < 4; ++r) {
        if constexpr (WMODE == 0)
          ((float*)C)[(size_t)(row + r) * 4096 + col] = acc[M][N][r];
        else
          ((__hip_bfloat16*)C)[(size_t)(row + r) * 4096 + col] =
              __float2bfloat16(acc[M][N][r]);
      }
    }
}

// m97-structure GEMM kept for the KV projection (fused K | V^T epilogue)
__global__ __launch_bounds__(256) void gemm_kv(
    const __hip_bfloat16* __restrict__ A, const __hip_bfloat16* __restrict__ BT,
    __hip_bfloat16* __restrict__ Kb, __hip_bfloat16* __restrict__ VT, int M,
    int N, int K) {
  __shared__ __align__(16) __hip_bfloat16 As[128 * 32];
  __shared__ __align__(16) __hip_bfloat16 Bs[128 * 32];
  const int tid = threadIdx.x, lane = tid & 63, w = tid >> 6;
  const int l15 = lane & 15, l4 = lane >> 4;
  const int bm = blockIdx.y * 128, bn = blockIdx.x * 128;
  const int wr = (w >> 1) * 64, wc = (w & 1) * 64;
  const int srow = lane >> 2, scol = (lane & 3) * 8;
  const __hip_bfloat16* ga = &A[(size_t)(bm + w * 16 + srow) * K + scol];
  const __hip_bfloat16* gb = &BT[(size_t)(bn + w * 16 + srow) * K + scol];
  __hip_bfloat16* la0 = &As[w * 512];
  __hip_bfloat16* la1 = &As[(w + 4) * 512];
  __hip_bfloat16* lb0 = &Bs[w * 512];
  __hip_bfloat16* lb1 = &Bs[(w + 4) * 512];
  f32x4 acc[4][4] = {};

  for (int k0 = 0; k0 < K; k0 += 32) {
    gload16(ga, la0);
    gload16(ga + (size_t)64 * K, la1);
    gload16(gb, lb0);
    gload16(gb + (size_t)64 * K, lb1);
    ga += 32;
    gb += 32;
    __syncthreads();
    bf16x8 af[4], bfr[4];
#pragma unroll
    for (int m = 0; m < 4; ++m)
      af[m] = *reinterpret_cast<const bf16x8*>(
          &As[(wr + m * 16 + l15) * 32 + l4 * 8]);
#pragma unroll
    for (int n = 0; n < 4; ++n)
      bfr[n] = *reinterpret_cast<const bf16x8*>(
          &Bs[(wc + n * 16 + l15) * 32 + l4 * 8]);
#pragma unroll
    for (int m = 0; m < 4; ++m)
#pragma unroll
      for (int n = 0; n < 4; ++n)
        acc[m][n] = __builtin_amdgcn_mfma_f32_16x16x32_bf16(af[m], bfr[n],
                                                            acc[m][n], 0, 0, 0);
    __syncthreads();
  }

#pragma unroll
  for (int m = 0; m < 4; ++m)
#pragma unroll
    for (int n = 0; n < 4; ++n)
#pragma unroll
      for (int r = 0; r < 4; ++r) {
        const int row = bm + wr + m * 16 + l4 * 4 + r;
        const int col = bn + wc + n * 16 + l15;
        if (col < 512) {
          Kb[(size_t)row * 512 + col] = __float2bfloat16(acc[m][n][r]);
        } else {
          const int b = row >> 11, s = row & 2047;
          VT[(size_t)(b * 512 + (col - 512)) * 2048 + s] =
              __float2bfloat16(acc[m][n][r]);
        }
      }
}

// Flash GQA attention (unchanged from round 3)
__global__ __launch_bounds__(512, 4) void attn_kernel(
    const __hip_bfloat16* __restrict__ Q, const __hip_bfloat16* __restrict__ Kb,
    const __hip_bfloat16* __restrict__ VT, __hip_bfloat16* __restrict__ O) {
  __shared__ __align__(16) __hip_bfloat16 Kbuf[2][64 * 128];
  __shared__ __align__(16) __hip_bfloat16 Vbuf[2][128 * 64];
  const int tid = threadIdx.x, lane = tid & 63, w = tid >> 6;
  const int l15 = lane & 15, g = (lane >> 4) & 3;
  const int d = blockIdx.x;
  const int xg = d & 7, hh = (d >> 3) & 7, pr = d >> 6;
  const int bh = xg * 8 + hh;
  const int b = bh >> 5, h = bh & 31, kvh = (bh & 31) >> 3;
  const char* kbase = (const char*)Kb + (size_t)(b * S_LEN) * 1024 + kvh * 256;
  const char* vbase = (const char*)VT + (size_t)(b * 512 + kvh * 128) * 4096;
  const __hip_bfloat16* qbase =
      Q + (size_t)(b * S_LEN) * DMODEL + (size_t)h * DKH;
  __hip_bfloat16* obase = O + (size_t)(b * S_LEN) * DMODEL + (size_t)h * DKH;
  const int krr = lane >> 4, kcb = (lane & 15) * 16;
  const int vrr = lane >> 3, vcb = (lane & 7) * 16;
  char* klds = (char*)&Kbuf[0][0] + w * 2048;
  char* vlds = (char*)&Vbuf[0][0] + w * 2048;
  const int swr = (l15 & 7) * 16;

  int par = 0;
  for (int ph = 0; ph < 2; ++ph) {
    const int pp = ph ? (15 - pr) : pr;
    const int qw = pp * 128 + w * 16;
    const int qa = qw + l15;
    bf16x8 qf[4];
#pragma unroll
    for (int kb = 0; kb < 4; ++kb)
      qf[kb] = *reinterpret_cast<const bf16x8*>(
          &qbase[(size_t)(qw + l15) * DMODEL + kb * 32 + g * 8]);
    float mrow = -INFINITY, lrow = 0.f;
    f32x4 oacc[8] = {};
    const int t0 = pp * 2;
    {
      const int kv0 = t0 * 64;
#pragma unroll
      for (int i = 0; i < 2; ++i) {
        const int rr = 8 * w + 4 * i + krr;
        gload16(kbase + (size_t)(kv0 + rr) * 1024 + (kcb ^ ((rr & 7) * 16)),
                klds + par * 16384 + i * 1024);
        const int r2 = 16 * w + 8 * i + vrr;
        gload16(vbase + (size_t)r2 * 4096 + kv0 * 2 + (vcb ^ ((r2 & 7) * 16)),
                vlds + par * 16384 + i * 1024);
      }
    }
    for (int t = t0; t < 32; ++t) {
      __syncthreads();
      if (t + 1 < 32) {
        const int kv0 = (t + 1) * 64;
        const int np = par ^ 1;
#pragma unroll
        for (int i = 0; i < 2; ++i) {
          const int rr = 8 * w + 4 * i + krr;
          gload16(kbase + (size_t)(kv0 + rr) * 1024 + (kcb ^ ((rr & 7) * 16)),
                  klds + np * 16384 + i * 1024);
          const int r2 = 16 * w + 8 * i + vrr;
          gload16(vbase + (size_t)r2 * 4096 + kv0 * 2 + (vcb ^ ((r2 & 7) * 16)),
                  vlds + np * 16384 + i * 1024);
        }
      }
      const char* kp = (const char*)&Kbuf[0][0] + par * 16384;
      const char* vp = (const char*)&Vbuf[0][0] + par * 16384;
      f32x4 sT[4];
#pragma unroll
      for (int c = 0; c < 4; ++c) {
        f32x4 s = {};
#pragma unroll
        for (int kb = 0; kb < 4; ++kb) {
          const bf16x8 kf = *reinterpret_cast<const bf16x8*>(
              kp + (16 * c + l15) * 256 + ((kb * 64 + g * 16) ^ swr));
          s = __builtin_amdgcn_mfma_f32_16x16x32_bf16(kf, qf[kb], s, 0, 0, 0);
        }
        sT[c] = s;
      }
      const int dthr = qa - t * 64 - 4 * g;
      float m8 = -INFINITY;
#pragma unroll
      for (int c = 0; c < 4; ++c)
#pragma unroll
        for (int r = 0; r < 4; ++r) {
          const float v =
              (16 * c + r > dthr) ? sT[c][r] * 0.08838834764831843f : -1e9f;
          sT[c][r] = v;
          m8 = fmaxf(m8, v);
        }
      m8 = fmaxf(m8, __shfl_xor(m8, 16));
      m8 = fmaxf(m8, __shfl_xor(m8, 32));
      if (!__all(m8 - mrow <= 8.0f)) {
        const float mn = fmaxf(mrow, m8);
        const float al = __expf(mrow - mn);
        mrow = mn;
        lrow *= al;
#pragma unroll
        for (int n = 0; n < 8; ++n)
#pragma unroll
          for (int r = 0; r < 4; ++r) oacc[n][r] *= al;
      }
      float ps = 0.f;
#pragma unroll
      for (int c = 0; c < 4; ++c)
#pragma unroll
        for (int r = 0; r < 4; ++r) {
          const float e = __expf(sT[c][r] - mrow);
          sT[c][r] = e;
          ps += e;
        }
      ps += __shfl_xor(ps, 16);
      ps += __shfl_xor(ps, 32);
      lrow += ps;
      unsigned P0[4], P1[4];
#pragma unroll
      for (int c = 0; c < 4; ++c) {
        P0[c] = cvt_pk(sT[c][0], sT[c][1]);
        P1[c] = cvt_pk(sT[c][2], sT[c][3]);
      }
      const int sl_lo = l15 + ((g & 1) << 5);
      const int sl_hi = sl_lo + 16;
      const bool hi = (g & 2) != 0;
#pragma unroll
      for (int ks = 0; ks < 2; ++ks) {
        const int a0 = (int)P0[2 * ks], a1 = (int)P1[2 * ks];
        const int b0 = (int)P0[2 * ks + 1], b1 = (int)P1[2 * ks + 1];
        const unsigned s0a = __shfl(a0, sl_lo), s0b = __shfl(b0, sl_lo);
        const unsigned s1a = __shfl(a1, sl_lo), s1b = __shfl(b1, sl_lo);
        const unsigned s2a = __shfl(a0, sl_hi), s2b = __shfl(b0, sl_hi);
        const unsigned s3a = __shfl(a1, sl_hi), s3b = __shfl(b1, sl_hi);
        PU pu;
        pu.u[0] = hi ? s0b : s0a;
        pu.u[1] = hi ? s1b : s1a;
        pu.u[2] = hi ? s2b : s2a;
        pu.u[3] = hi ? s3b : s3a;
#pragma unroll
        for (int n = 0; n < 8; ++n) {
          const bf16x8 vf = *reinterpret_cast<const bf16x8*>(
              vp + (16 * n + l15) * 128 + ((ks * 64 + g * 16) ^ swr));
          oacc[n] =
              __builtin_amdgcn_mfma_f32_16x16x32_bf16(vf, pu.v, oacc[n], 0, 0, 0);
        }
      }
      par ^= 1;
    }
    const float rinv = 1.f / lrow;
    __hip_bfloat16* orow = obase + (size_t)(qw + l15) * DMODEL;
#pragma unroll
    for (int n = 0; n < 8; ++n) {
      uint2 st;
      st.x = cvt_pk(oacc[n][0] * rinv, oacc[n][1] * rinv);
      st.y = cvt_pk(oacc[n][2] * rinv, oacc[n][3] * rinv);
      *reinterpret_cast<uint2*>(&orow[16 * n + 4 * g]) = st;
    }
    __syncthreads();
  }
}

__global__ __launch_bounds__(128) void fixup_kernel(
    const __hip_bfloat16* __restrict__ VT, __hip_bfloat16* __restrict__ O) {
  const int b = blockIdx.x >> 5;
  const int h = blockIdx.x & 31;
  const int kvh = h >> 3;
  const int dk = threadIdx.x;
  const __hip_bfloat16* row = &VT[(size_t)(b * 512 + kvh * DKH + dk) * S_LEN];
  float s = 0.f;
  for (int i = 0; i < S_LEN / 8; ++i) {
    const bf16x8 v = *reinterpret_cast<const bf16x8*>(&row[i * 8]);
#pragma unroll
    for (int j = 0; j < 8; ++j) s += b2f(v[j]);
  }
  O[(size_t)(b * S_LEN + S_LEN - 1) * DMODEL + h * DKH + dk] =
      __float2bfloat16(s * (1.f / S_LEN));
}

extern "C" void kernel_launch(void* const* d_in, const int* in_sizes, int n_in,
                              void* d_out, int out_size, void* d_ws,
                              size_t ws_size, hipStream_t stream) {
  (void)in_sizes; (void)n_in; (void)out_size; (void)ws_size;
  const float* x = (const float*)d_in[0];
  const float* Wq = (const float*)d_in[1];
  const float* Wk = (const float*)d_in[2];
  const float* Wv = (const float*)d_in[3];
  const float* Wo = (const float*)d_in[4];
  float* out = (float*)d_out;

  char* ws = (char*)d_ws;
  __hip_bfloat16* xb  = (__hip_bfloat16*)(ws + 0);            // 32MB (reused as AO)
  __hip_bfloat16* WT0 = (__hip_bfloat16*)(ws + 33554432ull);  // 32MB
  __hip_bfloat16* KVT = (__hip_bfloat16*)(ws + 67108864ull);  // 8MB
  __hip_bfloat16* Qb  = (__hip_bfloat16*)(ws + 75497472ull);  // 32MB
  __hip_bfloat16* Kb  = (__hip_bfloat16*)(ws + 109051904ull); // 4MB
  __hip_bfloat16* VT  = (__hip_bfloat16*)(ws + 113246208ull); // 4MB
  __hip_bfloat16* AO  = xb;  // x dead after KV gemm

  const int M = 2 * S_LEN;  // 4096
  dim3 blk(256);

  cast_kernel<<<dim3(2048), blk, 0, stream>>>(x, xb, (M * DMODEL) / 4);
  transpose_cast_kernel<<<dim3(64, 64), blk, 0, stream>>>(Wq, WT0, DMODEL, DMODEL);
  gemm256<1><<<dim3(256), dim3(512), 0, stream>>>(xb, WT0, Qb);
  transpose_cast_kernel<<<dim3(8, 64), blk, 0, stream>>>(Wk, KVT, DMODEL, 512);
  transpose_cast_kernel<<<dim3(8, 64), blk, 0, stream>>>(Wv, KVT + 512ull * DMODEL, DMODEL, 512);
  gemm_kv<<<dim3(8, 32), blk, 0, stream>>>(xb, KVT, Kb, VT, M, 1024, DMODEL);
  attn_kernel<<<dim3(512), dim3(512), 0, stream>>>(Qb, Kb, VT, AO);
  fixup_kernel<<<dim3(64), dim3(128), 0, stream>>>(VT, AO);
  transpose_cast_kernel<<<dim3(64, 64), blk, 0, stream>>>(Wo, WT0, DMODEL, DMODEL);
  gemm256<0><<<dim3(256), dim3(512), 0, stream>>>(AO, WT0, out);
}

// Round 5
// 506.749 us; speedup vs baseline: 4.9788x; 1.0656x over previous
//
#include <hip/hip_runtime.h>
#include <hip/hip_bf16.h>

#define S_LEN 2048
#define DMODEL 4096
#define NQH 32
#define NKVH 4
#define DKH 128

typedef __attribute__((ext_vector_type(8))) short bf16x8;
typedef __attribute__((ext_vector_type(4))) float f32x4;

union PU { unsigned u[4]; bf16x8 v; };

__device__ __forceinline__ float b2f(short u) {
  union { float f; unsigned int i; } cv;
  cv.i = ((unsigned int)(unsigned short)u) << 16;
  return cv.f;
}

__device__ __forceinline__ unsigned cvt_pk(float lo, float hi) {
  unsigned r;
  asm("v_cvt_pk_bf16_f32 %0, %1, %2" : "=v"(r) : "v"(lo), "v"(hi));
  return r;
}

__device__ __forceinline__ void gload16(const void* g, void* l) {
  __builtin_amdgcn_global_load_lds(
      (const __attribute__((address_space(1))) void*)g,
      (__attribute__((address_space(3))) void*)l, 16, 0, 0);
}

// raw barrier: no implicit vmcnt(0) drain
#define BAR()                         \
  {                                   \
    asm volatile("" ::: "memory");    \
    __builtin_amdgcn_s_barrier();     \
    asm volatile("" ::: "memory");    \
  }

// f32 -> bf16 elementwise
__global__ __launch_bounds__(256) void cast_kernel(
    const float* __restrict__ in, __hip_bfloat16* __restrict__ out, int n4) {
  for (int i = blockIdx.x * 256 + threadIdx.x; i < n4; i += gridDim.x * 256) {
    const float4 v = reinterpret_cast<const float4*>(in)[i];
    __hip_bfloat16 t[4] = {__float2bfloat16(v.x), __float2bfloat16(v.y),
                           __float2bfloat16(v.z), __float2bfloat16(v.w)};
    reinterpret_cast<uint2*>(out)[i] = *reinterpret_cast<const uint2*>(t);
  }
}

// W f32 [K][N] -> WT bf16 [N][K]
__global__ __launch_bounds__(256) void transpose_cast_kernel(
    const float* __restrict__ W, __hip_bfloat16* __restrict__ WT, int K, int N) {
  __shared__ __align__(16) __hip_bfloat16 tile[64][64];
  const int tid = threadIdx.x;
  const int n0 = blockIdx.x * 64, k0 = blockIdx.y * 64;
#pragma unroll
  for (int i = 0; i < 2; ++i) {
    const int fid = i * 256 + tid;
    const int r = fid >> 3, cc = fid & 7;
    const float4 v0 = *reinterpret_cast<const float4*>(
        &W[(size_t)(k0 + r) * N + n0 + cc * 8]);
    const float4 v1 = *reinterpret_cast<const float4*>(
        &W[(size_t)(k0 + r) * N + n0 + cc * 8 + 4]);
    __hip_bfloat16 t[8] = {__float2bfloat16(v0.x), __float2bfloat16(v0.y),
                           __float2bfloat16(v0.z), __float2bfloat16(v0.w),
                           __float2bfloat16(v1.x), __float2bfloat16(v1.y),
                           __float2bfloat16(v1.z), __float2bfloat16(v1.w)};
    *reinterpret_cast<bf16x8*>(&tile[r][(cc ^ (r & 7)) << 3]) =
        *reinterpret_cast<const bf16x8*>(t);
  }
  __syncthreads();
  const int n = tid >> 2, kw = tid & 3;
#pragma unroll
  for (int i = 0; i < 2; ++i) {
    const int kc = kw + i * 4;
    __hip_bfloat16 t[8];
#pragma unroll
    for (int j = 0; j < 8; ++j) {
      const int r = kc * 8 + j;
      t[j] = tile[r][((((n >> 3) ^ (r & 7)) << 3)) + (n & 7)];
    }
    *reinterpret_cast<bf16x8*>(&WT[(size_t)(n0 + n) * K + k0 + kc * 8]) =
        *reinterpret_cast<const bf16x8*>(t);
  }
}

// ---------------- 8-phase 256x256 GEMM (4096^3, bf16 in) -------------------
// Round-5 revision: minimal LDS reads (24 ds_read_b128/tile/wave, each
// fragment read once and held in regs across its consumer phases) and
// minimal barriers (4/tile). Liveness/hazards:
//  ph(0,0): read A0(8),B0(4); stage (t+1).A1->pn  [A1(pn) last read t-1 ph(1,0)]
//  ph(0,1): read B1(4);       stage (t+1).B1->pn  [B1(pn) last read t-1 ph(0,1)]
//  ph(1,0): read A1(8);       stage (t+2).A0->pc  [A0(pc) reads done ph(0,0),
//                                                  all waves past BAR_b]
//  ph(1,1): (regs only)       stage (t+2).B0->pc  [B0 reads done ph(0,0)]
// Tile-top: vmcnt(4) (2 newest half-tiles stay in flight) + BAR publishes.
template <int WMODE>  // 0: f32 out, 1: bf16 out
__global__ __launch_bounds__(512, 2) void gemm256(
    const __hip_bfloat16* __restrict__ A, const __hip_bfloat16* __restrict__ BT,
    void* __restrict__ C) {
  __shared__ __align__(16) char ldsA[131072];
  const char* lds = &ldsA[0];
  const int tid = threadIdx.x, lane = tid & 63, w = tid >> 6;
  const int l15 = lane & 15, g = lane >> 4;
  const int wr = w >> 2, wcn = w & 3;
  const int id = blockIdx.x;
  const int swz = (id & 7) * 32 + (id >> 3);
  const int bm = (swz >> 4) * 256, bn = (swz & 15) * 256;
  const int row0 = tid >> 3;  // 0..63
  const int kbg = ((tid & 7) * 16) ^ ((row0 & 7) << 4);
  const char* Ab = (const char*)A;
  const char* Bb = (const char*)BT;
  const size_t aR = (size_t)(bm + row0) * 8192 + kbg;
  const size_t bR = (size_t)(bn + row0) * 8192 + kbg;
  char* ldsw = const_cast<char*>(lds) + w * 1024;
  const int sw = (l15 & 7) << 4;
  const int okk = (g * 16) ^ sw;
  const int rA = (wr * 64 + l15) * 128;
  const int rB = (wcn * 32 + l15) * 128;

  f32x4 acc[8][4] = {};

#define STG2(XR, XB, DST)            \
  gload16(XB + (XR), ldsw + (DST));  \
  gload16(XB + (XR) + 524288, ldsw + (DST) + 8192)

  // prologue: tile0 complete + tile1 A0,B0
  STG2(aR, Ab, 0);
  STG2(bR, Bb, 65536);
  STG2(aR + 1048576, Ab, 16384);
  STG2(bR + 1048576, Bb, 65536 + 16384);
  STG2(aR + 128, Ab, 32768);
  STG2(bR + 128, Bb, 65536 + 32768);

  for (int t = 0; t < 64; ++t) {
    const int pc = t & 1, pn = pc ^ 1;
    const int pA = pc * 32768, pB = 65536 + pc * 32768;
    const size_t s01 = (size_t)((t + 1 < 64) ? t + 1 : t - 1) * 128;
    const size_t s23 = (size_t)((t + 2 < 64) ? t + 2 : t) * 128;
    asm volatile("s_waitcnt vmcnt(4)" ::: "memory");  // tile t resident
    BAR();
    // ---- ph(0,0): read A0+B0, stage (t+1).A1, MFMA A0xB0
    bf16x8 a0[4][2], b0[2][2];
#pragma unroll
    for (int m = 0; m < 4; ++m)
#pragma unroll
      for (int kk = 0; kk < 2; ++kk)
        a0[m][kk] = *reinterpret_cast<const bf16x8*>(
            lds + pA + rA + m * 2048 + (okk ^ (kk << 6)));
#pragma unroll
    for (int n = 0; n < 2; ++n)
#pragma unroll
      for (int kk = 0; kk < 2; ++kk)
        b0[n][kk] = *reinterpret_cast<const bf16x8*>(
            lds + pB + rB + n * 2048 + (okk ^ (kk << 6)));
    STG2(aR + 1048576 + s01, Ab, pn * 32768 + 16384);
    BAR();
    __builtin_amdgcn_s_setprio(1);
#pragma unroll
    for (int kk = 0; kk < 2; ++kk)
#pragma unroll
      for (int m = 0; m < 4; ++m)
#pragma unroll
        for (int n = 0; n < 2; ++n)
          acc[m][n] = __builtin_amdgcn_mfma_f32_16x16x32_bf16(
              a0[m][kk], b0[n][kk], acc[m][n], 0, 0, 0);
    __builtin_amdgcn_s_setprio(0);
    // ---- ph(0,1): read B1, stage (t+1).B1, MFMA A0xB1
    bf16x8 b1[2][2];
#pragma unroll
    for (int n = 0; n < 2; ++n)
#pragma unroll
      for (int kk = 0; kk < 2; ++kk)
        b1[n][kk] = *reinterpret_cast<const bf16x8*>(
            lds + pB + 16384 + rB + n * 2048 + (okk ^ (kk << 6)));
    STG2(bR + 1048576 + s01, Bb, 65536 + pn * 32768 + 16384);
    BAR();
    __builtin_amdgcn_s_setprio(1);
#pragma unroll
    for (int kk = 0; kk < 2; ++kk)
#pragma unroll
      for (int m = 0; m < 4; ++m)
#pragma unroll
        for (int n = 0; n < 2; ++n)
          acc[m][2 + n] = __builtin_amdgcn_mfma_f32_16x16x32_bf16(
              a0[m][kk], b1[n][kk], acc[m][2 + n], 0, 0, 0);
    __builtin_amdgcn_s_setprio(0);
    // ---- ph(1,0): read A1, stage (t+2).A0, MFMA A1xB0
    bf16x8 a1[4][2];
#pragma unroll
    for (int m = 0; m < 4; ++m)
#pragma unroll
      for (int kk = 0; kk < 2; ++kk)
        a1[m][kk] = *reinterpret_cast<const bf16x8*>(
            lds + pA + 16384 + rA + m * 2048 + (okk ^ (kk << 6)));
    STG2(aR + s23, Ab, pc * 32768);
    BAR();
    __builtin_amdgcn_s_setprio(1);
#pragma unroll
    for (int kk = 0; kk < 2; ++kk)
#pragma unroll
      for (int m = 0; m < 4; ++m)
#pragma unroll
        for (int n = 0; n < 2; ++n)
          acc[4 + m][n] = __builtin_amdgcn_mfma_f32_16x16x32_bf16(
              a1[m][kk], b0[n][kk], acc[4 + m][n], 0, 0, 0);
    __builtin_amdgcn_s_setprio(0);
    // ---- ph(1,1): stage (t+2).B0, MFMA A1xB1 (regs only, no barrier)
    STG2(bR + s23, Bb, 65536 + pc * 32768);
    __builtin_amdgcn_s_setprio(1);
#pragma unroll
    for (int kk = 0; kk < 2; ++kk)
#pragma unroll
      for (int m = 0; m < 4; ++m)
#pragma unroll
        for (int n = 0; n < 2; ++n)
          acc[4 + m][2 + n] = __builtin_amdgcn_mfma_f32_16x16x32_bf16(
              a1[m][kk], b1[n][kk], acc[4 + m][2 + n], 0, 0, 0);
    __builtin_amdgcn_s_setprio(0);
  }
  asm volatile("s_waitcnt vmcnt(0)" ::: "memory");

  const int crow0 = bm + wr * 64 + g * 4;
  const int ccol0 = bn + wcn * 32 + l15;
#pragma unroll
  for (int M = 0; M < 8; ++M)
#pragma unroll
    for (int N = 0; N < 4; ++N) {
      const int row = crow0 + (M >> 2) * 128 + (M & 3) * 16;
      const int col = ccol0 + (N >> 1) * 128 + (N & 1) * 16;
#pragma unroll
      for (int r = 0; r < 4; ++r) {
        if constexpr (WMODE == 0)
          ((float*)C)[(size_t)(row + r) * 4096 + col] = acc[M][N][r];
        else
          ((__hip_bfloat16*)C)[(size_t)(row + r) * 4096 + col] =
              __float2bfloat16(acc[M][N][r]);
      }
    }
}

// m97-structure GEMM kept for the KV projection (fused K | V^T epilogue)
__global__ __launch_bounds__(256) void gemm_kv(
    const __hip_bfloat16* __restrict__ A, const __hip_bfloat16* __restrict__ BT,
    __hip_bfloat16* __restrict__ Kb, __hip_bfloat16* __restrict__ VT, int M,
    int N, int K) {
  __shared__ __align__(16) __hip_bfloat16 As[128 * 32];
  __shared__ __align__(16) __hip_bfloat16 Bs[128 * 32];
  const int tid = threadIdx.x, lane = tid & 63, w = tid >> 6;
  const int l15 = lane & 15, l4 = lane >> 4;
  const int bm = blockIdx.y * 128, bn = blockIdx.x * 128;
  const int wr = (w >> 1) * 64, wc = (w & 1) * 64;
  const int srow = lane >> 2, scol = (lane & 3) * 8;
  const __hip_bfloat16* ga = &A[(size_t)(bm + w * 16 + srow) * K + scol];
  const __hip_bfloat16* gb = &BT[(size_t)(bn + w * 16 + srow) * K + scol];
  __hip_bfloat16* la0 = &As[w * 512];
  __hip_bfloat16* la1 = &As[(w + 4) * 512];
  __hip_bfloat16* lb0 = &Bs[w * 512];
  __hip_bfloat16* lb1 = &Bs[(w + 4) * 512];
  f32x4 acc[4][4] = {};

  for (int k0 = 0; k0 < K; k0 += 32) {
    gload16(ga, la0);
    gload16(ga + (size_t)64 * K, la1);
    gload16(gb, lb0);
    gload16(gb + (size_t)64 * K, lb1);
    ga += 32;
    gb += 32;
    __syncthreads();
    bf16x8 af[4], bfr[4];
#pragma unroll
    for (int m = 0; m < 4; ++m)
      af[m] = *reinterpret_cast<const bf16x8*>(
          &As[(wr + m * 16 + l15) * 32 + l4 * 8]);
#pragma unroll
    for (int n = 0; n < 4; ++n)
      bfr[n] = *reinterpret_cast<const bf16x8*>(
          &Bs[(wc + n * 16 + l15) * 32 + l4 * 8]);
#pragma unroll
    for (int m = 0; m < 4; ++m)
#pragma unroll
      for (int n = 0; n < 4; ++n)
        acc[m][n] = __builtin_amdgcn_mfma_f32_16x16x32_bf16(af[m], bfr[n],
                                                            acc[m][n], 0, 0, 0);
    __syncthreads();
  }

#pragma unroll
  for (int m = 0; m < 4; ++m)
#pragma unroll
    for (int n = 0; n < 4; ++n)
#pragma unroll
      for (int r = 0; r < 4; ++r) {
        const int row = bm + wr + m * 16 + l4 * 4 + r;
        const int col = bn + wc + n * 16 + l15;
        if (col < 512) {
          Kb[(size_t)row * 512 + col] = __float2bfloat16(acc[m][n][r]);
        } else {
          const int b = row >> 11, s = row & 2047;
          VT[(size_t)(b * 512 + (col - 512)) * 2048 + s] =
              __float2bfloat16(acc[m][n][r]);
        }
      }
}

// Flash GQA attention (unchanged)
__global__ __launch_bounds__(512, 4) void attn_kernel(
    const __hip_bfloat16* __restrict__ Q, const __hip_bfloat16* __restrict__ Kb,
    const __hip_bfloat16* __restrict__ VT, __hip_bfloat16* __restrict__ O) {
  __shared__ __align__(16) __hip_bfloat16 Kbuf[2][64 * 128];
  __shared__ __align__(16) __hip_bfloat16 Vbuf[2][128 * 64];
  const int tid = threadIdx.x, lane = tid & 63, w = tid >> 6;
  const int l15 = lane & 15, g = (lane >> 4) & 3;
  const int d = blockIdx.x;
  const int xg = d & 7, hh = (d >> 3) & 7, pr = d >> 6;
  const int bh = xg * 8 + hh;
  const int b = bh >> 5, h = bh & 31, kvh = (bh & 31) >> 3;
  const char* kbase = (const char*)Kb + (size_t)(b * S_LEN) * 1024 + kvh * 256;
  const char* vbase = (const char*)VT + (size_t)(b * 512 + kvh * 128) * 4096;
  const __hip_bfloat16* qbase =
      Q + (size_t)(b * S_LEN) * DMODEL + (size_t)h * DKH;
  __hip_bfloat16* obase = O + (size_t)(b * S_LEN) * DMODEL + (size_t)h * DKH;
  const int krr = lane >> 4, kcb = (lane & 15) * 16;
  const int vrr = lane >> 3, vcb = (lane & 7) * 16;
  char* klds = (char*)&Kbuf[0][0] + w * 2048;
  char* vlds = (char*)&Vbuf[0][0] + w * 2048;
  const int swr = (l15 & 7) * 16;

  int par = 0;
  for (int ph = 0; ph < 2; ++ph) {
    const int pp = ph ? (15 - pr) : pr;
    const int qw = pp * 128 + w * 16;
    const int qa = qw + l15;
    bf16x8 qf[4];
#pragma unroll
    for (int kb = 0; kb < 4; ++kb)
      qf[kb] = *reinterpret_cast<const bf16x8*>(
          &qbase[(size_t)(qw + l15) * DMODEL + kb * 32 + g * 8]);
    float mrow = -INFINITY, lrow = 0.f;
    f32x4 oacc[8] = {};
    const int t0 = pp * 2;
    {
      const int kv0 = t0 * 64;
#pragma unroll
      for (int i = 0; i < 2; ++i) {
        const int rr = 8 * w + 4 * i + krr;
        gload16(kbase + (size_t)(kv0 + rr) * 1024 + (kcb ^ ((rr & 7) * 16)),
                klds + par * 16384 + i * 1024);
        const int r2 = 16 * w + 8 * i + vrr;
        gload16(vbase + (size_t)r2 * 4096 + kv0 * 2 + (vcb ^ ((r2 & 7) * 16)),
                vlds + par * 16384 + i * 1024);
      }
    }
    for (int t = t0; t < 32; ++t) {
      __syncthreads();
      if (t + 1 < 32) {
        const int kv0 = (t + 1) * 64;
        const int np = par ^ 1;
#pragma unroll
        for (int i = 0; i < 2; ++i) {
          const int rr = 8 * w + 4 * i + krr;
          gload16(kbase + (size_t)(kv0 + rr) * 1024 + (kcb ^ ((rr & 7) * 16)),
                  klds + np * 16384 + i * 1024);
          const int r2 = 16 * w + 8 * i + vrr;
          gload16(vbase + (size_t)r2 * 4096 + kv0 * 2 + (vcb ^ ((r2 & 7) * 16)),
                  vlds + np * 16384 + i * 1024);
        }
      }
      const char* kp = (const char*)&Kbuf[0][0] + par * 16384;
      const char* vp = (const char*)&Vbuf[0][0] + par * 16384;
      f32x4 sT[4];
#pragma unroll
      for (int c = 0; c < 4; ++c) {
        f32x4 s = {};
#pragma unroll
        for (int kb = 0; kb < 4; ++kb) {
          const bf16x8 kf = *reinterpret_cast<const bf16x8*>(
              kp + (16 * c + l15) * 256 + ((kb * 64 + g * 16) ^ swr));
          s = __builtin_amdgcn_mfma_f32_16x16x32_bf16(kf, qf[kb], s, 0, 0, 0);
        }
        sT[c] = s;
      }
      const int dthr = qa - t * 64 - 4 * g;
      float m8 = -INFINITY;
#pragma unroll
      for (int c = 0; c < 4; ++c)
#pragma unroll
        for (int r = 0; r < 4; ++r) {
          const float v =
              (16 * c + r > dthr) ? sT[c][r] * 0.08838834764831843f : -1e9f;
          sT[c][r] = v;
          m8 = fmaxf(m8, v);
        }
      m8 = fmaxf(m8, __shfl_xor(m8, 16));
      m8 = fmaxf(m8, __shfl_xor(m8, 32));
      if (!__all(m8 - mrow <= 8.0f)) {
        const float mn = fmaxf(mrow, m8);
        const float al = __expf(mrow - mn);
        mrow = mn;
        lrow *= al;
#pragma unroll
        for (int n = 0; n < 8; ++n)
#pragma unroll
          for (int r = 0; r < 4; ++r) oacc[n][r] *= al;
      }
      float ps = 0.f;
#pragma unroll
      for (int c = 0; c < 4; ++c)
#pragma unroll
        for (int r = 0; r < 4; ++r) {
          const float e = __expf(sT[c][r] - mrow);
          sT[c][r] = e;
          ps += e;
        }
      ps += __shfl_xor(ps, 16);
      ps += __shfl_xor(ps, 32);
      lrow += ps;
      unsigned P0[4], P1[4];
#pragma unroll
      for (int c = 0; c < 4; ++c) {
        P0[c] = cvt_pk(sT[c][0], sT[c][1]);
        P1[c] = cvt_pk(sT[c][2], sT[c][3]);
      }
      const int sl_lo = l15 + ((g & 1) << 5);
      const int sl_hi = sl_lo + 16;
      const bool hi = (g & 2) != 0;
#pragma unroll
      for (int ks = 0; ks < 2; ++ks) {
        const int a0 = (int)P0[2 * ks], a1 = (int)P1[2 * ks];
        const int b0 = (int)P0[2 * ks + 1], b1 = (int)P1[2 * ks + 1];
        const unsigned s0a = __shfl(a0, sl_lo), s0b = __shfl(b0, sl_lo);
        const unsigned s1a = __shfl(a1, sl_lo), s1b = __shfl(b1, sl_lo);
        const unsigned s2a = __shfl(a0, sl_hi), s2b = __shfl(b0, sl_hi);
        const unsigned s3a = __shfl(a1, sl_hi), s3b = __shfl(b1, sl_hi);
        PU pu;
        pu.u[0] = hi ? s0b : s0a;
        pu.u[1] = hi ? s1b : s1a;
        pu.u[2] = hi ? s2b : s2a;
        pu.u[3] = hi ? s3b : s3a;
#pragma unroll
        for (int n = 0; n < 8; ++n) {
          const bf16x8 vf = *reinterpret_cast<const bf16x8*>(
              vp + (16 * n + l15) * 128 + ((ks * 64 + g * 16) ^ swr));
          oacc[n] =
              __builtin_amdgcn_mfma_f32_16x16x32_bf16(vf, pu.v, oacc[n], 0, 0, 0);
        }
      }
      par ^= 1;
    }
    const float rinv = 1.f / lrow;
    __hip_bfloat16* orow = obase + (size_t)(qw + l15) * DMODEL;
#pragma unroll
    for (int n = 0; n < 8; ++n) {
      uint2 st;
      st.x = cvt_pk(oacc[n][0] * rinv, oacc[n][1] * rinv);
      st.y = cvt_pk(oacc[n][2] * rinv, oacc[n][3] * rinv);
      *reinterpret_cast<uint2*>(&orow[16 * n + 4 * g]) = st;
    }
    __syncthreads();
  }
}

__global__ __launch_bounds__(128) void fixup_kernel(
    const __hip_bfloat16* __restrict__ VT, __hip_bfloat16* __restrict__ O) {
  const int b = blockIdx.x >> 5;
  const int h = blockIdx.x & 31;
  const int kvh = h >> 3;
  const int dk = threadIdx.x;
  const __hip_bfloat16* row = &VT[(size_t)(b * 512 + kvh * DKH + dk) * S_LEN];
  float s = 0.f;
  for (int i = 0; i < S_LEN / 8; ++i) {
    const bf16x8 v = *reinterpret_cast<const bf16x8*>(&row[i * 8]);
#pragma unroll
    for (int j = 0; j < 8; ++j) s += b2f(v[j]);
  }
  O[(size_t)(b * S_LEN + S_LEN - 1) * DMODEL + h * DKH + dk] =
      __float2bfloat16(s * (1.f / S_LEN));
}

extern "C" void kernel_launch(void* const* d_in, const int* in_sizes, int n_in,
                              void* d_out, int out_size, void* d_ws,
                              size_t ws_size, hipStream_t stream) {
  (void)in_sizes; (void)n_in; (void)out_size; (void)ws_size;
  const float* x = (const float*)d_in[0];
  const float* Wq = (const float*)d_in[1];
  const float* Wk = (const float*)d_in[2];
  const float* Wv = (const float*)d_in[3];
  const float* Wo = (const float*)d_in[4];
  float* out = (float*)d_out;

  char* ws = (char*)d_ws;
  __hip_bfloat16* xb  = (__hip_bfloat16*)(ws + 0);            // 32MB (reused as AO)
  __hip_bfloat16* WT0 = (__hip_bfloat16*)(ws + 33554432ull);  // 32MB
  __hip_bfloat16* KVT = (__hip_bfloat16*)(ws + 67108864ull);  // 8MB
  __hip_bfloat16* Qb  = (__hip_bfloat16*)(ws + 75497472ull);  // 32MB
  __hip_bfloat16* Kb  = (__hip_bfloat16*)(ws + 109051904ull); // 4MB
  __hip_bfloat16* VT  = (__hip_bfloat16*)(ws + 113246208ull); // 4MB
  __hip_bfloat16* AO  = xb;  // x dead after KV gemm

  const int M = 2 * S_LEN;  // 4096
  dim3 blk(256);

  cast_kernel<<<dim3(2048), blk, 0, stream>>>(x, xb, (M * DMODEL) / 4);
  transpose_cast_kernel<<<dim3(64, 64), blk, 0, stream>>>(Wq, WT0, DMODEL, DMODEL);
  gemm256<1><<<dim3(256), dim3(512), 0, stream>>>(xb, WT0, Qb);
  transpose_cast_kernel<<<dim3(8, 64), blk, 0, stream>>>(Wk, KVT, DMODEL, 512);
  transpose_cast_kernel<<<dim3(8, 64), blk, 0, stream>>>(Wv, KVT + 512ull * DMODEL, DMODEL, 512);
  gemm_kv<<<dim3(8, 32), blk, 0, stream>>>(xb, KVT, Kb, VT, M, 1024, DMODEL);
  attn_kernel<<<dim3(512), dim3(512), 0, stream>>>(Qb, Kb, VT, AO);
  fixup_kernel<<<dim3(64), dim3(128), 0, stream>>>(VT, AO);
  transpose_cast_kernel<<<dim3(64, 64), blk, 0, stream>>>(Wo, WT0, DMODEL, DMODEL);
  gemm256<0><<<dim3(256), dim3(512), 0, stream>>>(AO, WT0, out);
}